// Round 4
// baseline (11352.887 us; speedup 1.0000x reference)
//
#include <hip/hip_runtime.h>
#include <cstdint>
#include <cstddef>

// Problem dims
#define BDIM 32
#define TDIM 2048
#define IDIM 256
#define HDIM 256
#define CHUNK 128
#define NCHUNK (TDIM / CHUNK)

using short8 = __attribute__((ext_vector_type(8))) short;
using f32x4  = __attribute__((ext_vector_type(4))) float;
typedef _Float16 half2v __attribute__((ext_vector_type(2)));

__device__ __forceinline__ uint16_t f2bf(float f) {
  uint32_t u = __float_as_uint(f);
  uint32_t r = u + 0x7fffu + ((u >> 16) & 1u);   // RNE
  return (uint16_t)(r >> 16);
}
__device__ __forceinline__ uint16_t f2h_bits(float f) {
  _Float16 h = (_Float16)f;
  return __builtin_bit_cast(uint16_t, h);
}
__device__ __forceinline__ half2v as_h2(uint32_t u) {
  return __builtin_bit_cast(half2v, u);
}
__device__ __forceinline__ float h2lo(uint32_t u) { return (float)as_h2(u)[0]; }
__device__ __forceinline__ float h2hi(uint32_t u) { return (float)as_h2(u)[1]; }

#if __has_builtin(__builtin_amdgcn_fdot2)
__device__ __forceinline__ float DOT2(half2v a, half2v b, float c) {
  return __builtin_amdgcn_fdot2(a, b, c, false);
}
#else
__device__ __forceinline__ float DOT2(half2v a, half2v b, float c) {
  return c + (float)a[0] * (float)b[0] + (float)a[1] * (float)b[1];
}
#endif

__device__ __forceinline__ float sigmoidf_fast(float x) {
  return 1.f / (1.f + __expf(-x));
}
__device__ __forceinline__ float tanhf_fast(float x) {
  float a = fabsf(x);
  float e = __expf(2.f * a);
  float t = 1.f - 2.f / (e + 1.f);
  return copysignf(t, x);
}

// ---------------- prep kernels ----------------

__global__ void k_cvt4(const float* __restrict__ src, uint16_t* __restrict__ dst, int n4) {
  int i = blockIdx.x * blockDim.x + threadIdx.x;
  if (i >= n4) return;
  const float4 v = ((const float4*)src)[i];
  ushort4 o;
  o.x = f2bf(v.x); o.y = f2bf(v.y); o.z = f2bf(v.z); o.w = f2bf(v.w);
  ((ushort4*)dst)[i] = o;
}

__global__ void k_zero_u32(uint32_t* __restrict__ p, int n) {
  int i = blockIdx.x * blockDim.x + threadIdx.x;
  if (i < n) p[i] = 0u;
}

// wcat[j][k] (bf16), j: dir=j>>10, n=(j&1023)>>2, g=j&3 -> Wih_dir row g*256+n
__global__ void k_build_wcat(const float* __restrict__ wf, const float* __restrict__ wb,
                             const float* __restrict__ biasf, const float* __restrict__ biasb,
                             uint16_t* __restrict__ wcat, float* __restrict__ biasp) {
  int id = blockIdx.x * 256 + threadIdx.x;    // 0 .. 524287
  int k = id & 255;
  int j = id >> 8;
  int dir = j >> 10;
  int jj = j & 1023;
  int n = jj >> 2;
  int g = jj & 3;
  const float* W = dir ? wb : wf;
  wcat[id] = f2bf(W[(g * 256 + n) * 256 + k]);
  if (k == 0) biasp[j] = (dir ? biasb : biasf)[g * 256 + n];
}

// wrec3 (f16 h2-packed u32): flat = ((((dir*4+q)*8+kq)*16+j)*64+n)*4+g
// value = pack(W[g*256+q*64+n][kq*32+2j], W[..][kq*32+2j+1])
__global__ void k_build_wrec3(const float* __restrict__ whf, const float* __restrict__ whb,
                              uint32_t* __restrict__ wrec3) {
  int id = blockIdx.x * 256 + threadIdx.x;   // 0 .. 262143
  int g   = id & 3;
  int n   = (id >> 2) & 63;
  int j   = (id >> 8) & 15;
  int kq  = (id >> 12) & 7;
  int qq  = (id >> 15) & 3;
  int dir = (id >> 17) & 1;
  const float* W = dir ? whb : whf;
  const int row = g * 256 + qq * 64 + n;
  const int k0  = kq * 32 + 2 * j;
  const uint32_t lo = f2h_bits(W[row * 256 + k0]);
  const uint32_t hi = f2h_bits(W[row * 256 + k0 + 1]);
  const int oidx = ((((dir * 4 + qq) * 8 + kq) * 16 + j) * 64 + n) * 4 + g;
  wrec3[oidx] = lo | (hi << 16);
}

// ---------------- persistent bidirectional LSTM ----------------
// 256 WGs (1/CU): WG = (pair = bid&63 -> (b,dir), q = bid>>6 n-quarter).
// 512 threads = 8 waves: wave kq handles k in [kq*32, kq*32+32), lane = n within quarter.
// Whh slice lives in 16 uint4 VGPRs per thread for the whole kernel.
// Per chunk of 128 steps, the WG first computes its own xW slice via MFMA
// (private double-buffered region), then runs 128 recurrence steps with
// per-step h-broadcast between the pair's 4 WGs (agent-scope atomics + counters).
__global__ __launch_bounds__(512, 2) void k_lstm_persist(
    const float* __restrict__ x,          // [32][2048][256] f32
    const uint16_t* __restrict__ wcat,    // [2048][256] bf16
    const float* __restrict__ biasp,      // [2048]
    const uint32_t* __restrict__ wrec3,   // packed Whh f16
    uint16_t* __restrict__ xwp_all,       // [256 WG][2][128][256] f16
    uint32_t* __restrict__ hcat32,        // [B][T][256] u32 (=512 f16)
    uint32_t* __restrict__ cnt) {         // [64*4] progress counters
  // carve LDS from one big block (84KB forces 1 WG/CU -> all 256 co-resident)
  __shared__ uint4 ldsbig[84 * 1024 / 16];
  f32x4*    partsh = (f32x4*)ldsbig;                    // [7][64]  (7168 B)
  uint32_t* h2lds  = (uint32_t*)(ldsbig + 448);         // [128]    (512 B)

  const int bid  = blockIdx.x;
  const int pair = bid & 63;
  const int q    = bid >> 6;
  const int b    = pair >> 1;
  const int dir  = pair & 1;
  const int tid  = threadIdx.x;
  const int kq   = tid >> 6;        // wave id 0..7
  const int lane = tid & 63;

  // ---- load Whh slice into registers (once) ----
  uint4 wr[16];
  {
    const uint4* wsrc = (const uint4*)wrec3 + ((((dir * 4 + q) * 8 + kq) * 16) * 64 + lane);
#pragma unroll
    for (int j = 0; j < 16; ++j) wr[j] = wsrc[j * 64];
  }

  if (tid < 128) h2lds[tid] = 0u;
  float creg = 0.f;
  __syncthreads();

  uint16_t* xwp = xwp_all + (size_t)bid * (2 * CHUNK * 256);
  const int l15 = lane & 15;
  const int lg  = lane >> 4;
  const int colbase = dir * 1024 + q * 256;
  const uint32_t cmy = pair * 4 + q;

  // ---- private-slice input GEMM for one chunk ----
  auto gemm_chunk = [&](int ck) {
    const int p = ck & 1;
    const int sl0 = kq * 16;
    const int slA = sl0 + l15;
    const int tA = dir ? (TDIM - 1 - (ck * CHUNK + slA)) : (ck * CHUNK + slA);
    const float* Abase = x + ((size_t)(b * TDIM + tA)) * 256 + lg * 8;
    uint16_t* xo = xwp + (size_t)p * (CHUNK * 256);
#pragma unroll
    for (int np = 0; np < 2; ++np) {
      f32x4 acc[8] = {};
#pragma unroll
      for (int ks = 0; ks < 8; ++ks) {
        const float4 f0 = *(const float4*)(Abase + ks * 32);
        const float4 f1 = *(const float4*)(Abase + ks * 32 + 4);
        short8 a;
        a[0] = (short)f2bf(f0.x); a[1] = (short)f2bf(f0.y);
        a[2] = (short)f2bf(f0.z); a[3] = (short)f2bf(f0.w);
        a[4] = (short)f2bf(f1.x); a[5] = (short)f2bf(f1.y);
        a[6] = (short)f2bf(f1.z); a[7] = (short)f2bf(f1.w);
#pragma unroll
        for (int nf = 0; nf < 8; ++nf) {
          const uint16_t* Bp = wcat + (size_t)(colbase + np * 128 + nf * 16 + l15) * 256 + ks * 32 + lg * 8;
          const short8 bfr = *(const short8*)Bp;
          acc[nf] = __builtin_amdgcn_mfma_f32_16x16x32_bf16(a, bfr, acc[nf], 0, 0, 0);
        }
      }
#pragma unroll
      for (int nf = 0; nf < 8; ++nf) {
        const int l = np * 128 + nf * 16 + l15;
        const float bv = biasp[colbase + l];
#pragma unroll
        for (int r = 0; r < 4; ++r) {
          const int row = sl0 + lg * 4 + r;
          xo[row * 256 + l] = f2h_bits(acc[nf][r] + bv);
        }
      }
    }
  };

  gemm_chunk(0);

  for (int ck = 0; ck < NCHUNK; ++ck) {
    if (ck + 1 < NCHUNK) gemm_chunk(ck + 1);
    const uint16_t* xin = xwp + (size_t)(ck & 1) * (CHUNK * 256);

    for (int sl = 0; sl < CHUNK; ++sl) {
      const int s = ck * CHUNK + sl;
      const int t = dir ? (TDIM - 1 - s) : s;

      // prefetch this step's xW gate quad (wave 0 consumes it)
      uint2 xv; xv.x = 0u; xv.y = 0u;
      if (tid < 64) xv = *(const uint2*)(xin + sl * 256 + tid * 4);

      // h broadcast registers
      const uint32_t h0 = h2lds[lane];
      const uint32_t h1 = h2lds[64 + lane];
      float ai = 0.f, af = 0.f, ag = 0.f, ao = 0.f;
      const int rb = (kq & 3) * 16;
      if (kq < 4) {
#pragma unroll
        for (int j = 0; j < 16; ++j) {
          const uint32_t hw = __builtin_amdgcn_readlane(h0, rb + j);
          ai = DOT2(as_h2(wr[j].x), as_h2(hw), ai);
          af = DOT2(as_h2(wr[j].y), as_h2(hw), af);
          ag = DOT2(as_h2(wr[j].z), as_h2(hw), ag);
          ao = DOT2(as_h2(wr[j].w), as_h2(hw), ao);
        }
      } else {
#pragma unroll
        for (int j = 0; j < 16; ++j) {
          const uint32_t hw = __builtin_amdgcn_readlane(h1, rb + j);
          ai = DOT2(as_h2(wr[j].x), as_h2(hw), ai);
          af = DOT2(as_h2(wr[j].y), as_h2(hw), af);
          ag = DOT2(as_h2(wr[j].z), as_h2(hw), ag);
          ao = DOT2(as_h2(wr[j].w), as_h2(hw), ao);
        }
      }
      f32x4 pv; pv[0] = ai; pv[1] = af; pv[2] = ag; pv[3] = ao;
      if (kq > 0) partsh[(kq - 1) * 64 + lane] = pv;
      __syncthreads();                                   // b1

      const size_t rowbase = ((size_t)(b * TDIM + t)) * 256 + dir * 128;
      if (tid < 64) {
        f32x4 g = pv;
#pragma unroll
        for (int r = 0; r < 7; ++r) g += partsh[r * 64 + lane];
        const float gi = g[0] + h2lo(xv.x);
        const float gf = g[1] + h2hi(xv.x);
        const float gg = g[2] + h2lo(xv.y);
        const float go = g[3] + h2hi(xv.y);
        const float I = sigmoidf_fast(gi);
        const float F = sigmoidf_fast(gf);
        const float G = tanhf_fast(gg);
        const float O = sigmoidf_fast(go);
        creg = F * creg + I * G;
        const float h = O * tanhf_fast(creg);
        const uint32_t hb = (uint32_t)f2h_bits(h);
        const uint32_t hp = (uint32_t)__shfl((int)hb, tid | 1, 64);
        if ((tid & 1) == 0) {
          const uint32_t hv = (hb & 0xffffu) | (hp << 16);
          const int m = tid >> 1;                        // 0..31
          h2lds[q * 32 + m] = hv;                        // own slice, local
          __hip_atomic_store(&hcat32[rowbase + q * 32 + m], hv,
                             __ATOMIC_RELAXED, __HIP_MEMORY_SCOPE_AGENT);
        }
      }
      __syncthreads();                                   // b2 (drains vmcnt)
      if (tid == 0)
        __hip_atomic_store(&cnt[cmy], (uint32_t)(s + 1),
                           __ATOMIC_RELEASE, __HIP_MEMORY_SCOPE_AGENT);

      if (s + 1 < TDIM) {
        if (tid < 3) {
          const int qo = tid + (tid >= q ? 1 : 0);
          while (__hip_atomic_load(&cnt[pair * 4 + qo],
                                   __ATOMIC_ACQUIRE, __HIP_MEMORY_SCOPE_AGENT) <= (uint32_t)s)
            __builtin_amdgcn_s_sleep(2);
        }
        __syncthreads();                                 // b3
        if (tid < 96) {
          const int grp = tid >> 5;
          const int qo = grp + (grp >= q ? 1 : 0);
          const int ii = tid & 31;
          const uint32_t hv = __hip_atomic_load(&hcat32[rowbase + qo * 32 + ii],
                                                __ATOMIC_RELAXED, __HIP_MEMORY_SCOPE_AGENT);
          h2lds[qo * 32 + ii] = hv;
        }
        __syncthreads();                                 // b4
      }
    }
  }
}

// ---------------- LayerNorm + FC (MFMA) ----------------
__global__ __launch_bounds__(256) void k_lnfc2(
    const uint16_t* __restrict__ hcat,
    const float* __restrict__ lng, const float* __restrict__ lnb,
    const uint16_t* __restrict__ fcwb,  // [256][512] bf16
    const float* __restrict__ fcb,
    float* __restrict__ out) {
  __shared__ uint16_t lnh[64 * 520];
  __shared__ float slng[512], slnb[512];

  const int tid = threadIdx.x;
  const size_t bt0 = (size_t)blockIdx.x * 64;

  slng[tid] = lng[tid]; slng[tid + 256] = lng[tid + 256];
  slnb[tid] = lnb[tid]; slnb[tid + 256] = lnb[tid + 256];

  const int row = tid >> 2;
  const int part = tid & 3;
  const uint16_t* hrow = hcat + (bt0 + row) * 512;
  float s = 0.f, s2 = 0.f;
#pragma unroll
  for (int i = 0; i < 16; ++i) {
    const uint4 u = *(const uint4*)(hrow + (i * 4 + part) * 8);
    const float f0 = h2lo(u.x), f1 = h2hi(u.x), f2 = h2lo(u.y), f3 = h2hi(u.y);
    const float f4 = h2lo(u.z), f5 = h2hi(u.z), f6 = h2lo(u.w), f7 = h2hi(u.w);
    s  += ((f0 + f1) + (f2 + f3)) + ((f4 + f5) + (f6 + f7));
    s2 += ((f0*f0 + f1*f1) + (f2*f2 + f3*f3)) + ((f4*f4 + f5*f5) + (f6*f6 + f7*f7));
  }
  s  += __shfl_xor(s, 1, 64);  s  += __shfl_xor(s, 2, 64);
  s2 += __shfl_xor(s2, 1, 64); s2 += __shfl_xor(s2, 2, 64);
  const float mu = s * (1.f / 512.f);
  const float var = s2 * (1.f / 512.f) - mu * mu;
  const float rs = rsqrtf(var + 1e-5f);
  __syncthreads();

#pragma unroll
  for (int i = 0; i < 16; ++i) {
    const int kb = (i * 4 + part) * 8;
    const uint4 u = *(const uint4*)(hrow + kb);
    uint16_t tmp[8] __attribute__((aligned(16)));
    const float f[8] = { h2lo(u.x), h2hi(u.x), h2lo(u.y), h2hi(u.y),
                         h2lo(u.z), h2hi(u.z), h2lo(u.w), h2hi(u.w) };
#pragma unroll
    for (int e = 0; e < 8; ++e)
      tmp[e] = f2bf((f[e] - mu) * rs * slng[kb + e] + slnb[kb + e]);
    *(short8*)&lnh[row * 520 + kb] = *(const short8*)tmp;
  }
  __syncthreads();

  const int w = tid >> 6;
  const int lane = tid & 63;
  const int l15 = lane & 15;
  const int lg = lane >> 4;
  f32x4 acc[4][4] = {};
#pragma unroll
  for (int nf = 0; nf < 4; ++nf) {
    const uint16_t* bb = fcwb + (size_t)(w * 64 + nf * 16 + l15) * 512 + lg * 8;
#pragma unroll 4
    for (int k0 = 0; k0 < 16; ++k0) {
      const short8 bfr = *(const short8*)(bb + k0 * 32);
#pragma unroll
      for (int mf = 0; mf < 4; ++mf) {
        const short8 afr = *(const short8*)&lnh[(mf * 16 + l15) * 520 + k0 * 32 + lg * 8];
        acc[mf][nf] = __builtin_amdgcn_mfma_f32_16x16x32_bf16(afr, bfr, acc[mf][nf], 0, 0, 0);
      }
    }
  }
#pragma unroll
  for (int nf = 0; nf < 4; ++nf) {
    const int col = w * 64 + nf * 16 + l15;
    const float fv = fcb[col];
#pragma unroll
    for (int mf = 0; mf < 4; ++mf)
#pragma unroll
      for (int r = 0; r < 4; ++r)
        out[(bt0 + mf * 16 + lg * 4 + r) * 256 + col] = acc[mf][nf][r] + fv;
  }
}

// ---------------- launcher ----------------

extern "C" void kernel_launch(void* const* d_in, const int* in_sizes, int n_in,
                              void* d_out, int out_size, void* d_ws, size_t ws_size,
                              hipStream_t stream) {
  const float* x    = (const float*)d_in[0];
  const float* Wihf = (const float*)d_in[1];
  const float* Whhf = (const float*)d_in[2];
  const float* bf_  = (const float*)d_in[3];
  const float* Wihb = (const float*)d_in[4];
  const float* Whhb = (const float*)d_in[5];
  const float* bb_  = (const float*)d_in[6];
  const float* lng  = (const float*)d_in[7];
  const float* lnb  = (const float*)d_in[8];
  const float* fcW  = (const float*)d_in[9];
  const float* fcb  = (const float*)d_in[10];
  float* out = (float*)d_out;

  char* ws = (char*)d_ws;
  size_t off = 0;
  uint16_t* wcat  = (uint16_t*)(ws + off); off += (size_t)2048 * 256 * 2;          // 1.0 MB
  float*    biasp = (float*)(ws + off);    off += (size_t)2048 * 4;                // 8 KB
  uint32_t* wrec3 = (uint32_t*)(ws + off); off += (size_t)262144 * 4;              // 1.0 MB
  uint16_t* fcwb  = (uint16_t*)(ws + off); off += (size_t)256 * 512 * 2;           // 0.26 MB
  uint32_t* cnt   = (uint32_t*)(ws + off); off += 4096;                            // 4 KB
  uint16_t* xwp   = (uint16_t*)(ws + off); off += (size_t)256 * 2 * CHUNK * 256 * 2; // 33.6 MB
  uint16_t* hcat  = (uint16_t*)(ws + off); off += (size_t)65536 * 512 * 2;         // 67 MB
  (void)ws_size; (void)in_sizes; (void)n_in; (void)out_size;
  // total ~103 MB

  k_cvt4<<<128, 256, 0, stream>>>(fcW, fcwb, 131072 / 4);
  k_build_wcat<<<2048, 256, 0, stream>>>(Wihf, Wihb, bf_, bb_, wcat, biasp);
  k_build_wrec3<<<1024, 256, 0, stream>>>(Whhf, Whhb, wrec3);
  k_zero_u32<<<1, 256, 0, stream>>>(cnt, 256);

  k_lstm_persist<<<256, 512, 0, stream>>>(x, wcat, biasp, wrec3, xwp,
                                          (uint32_t*)hcat, cnt);

  k_lnfc2<<<1024, 256, 0, stream>>>(hcat, lng, lnb, fcwb, fcb, out);
}

// Round 7
// 11308.228 us; speedup vs baseline: 1.0039x; 1.0039x over previous
//
#include <hip/hip_runtime.h>
#include <cstdint>
#include <cstddef>

// Problem dims
#define BDIM 32
#define TDIM 2048
#define IDIM 256
#define HDIM 256
#define CHUNK 128
#define NCHUNK (TDIM / CHUNK)
#define HROW 264   // hbuf row stride in f16 (256 + 8 pad)

using short8 = __attribute__((ext_vector_type(8))) short;
using f32x4  = __attribute__((ext_vector_type(4))) float;
typedef _Float16 f16x8 __attribute__((ext_vector_type(8)));

__device__ __forceinline__ uint16_t f2bf(float f) {
  uint32_t u = __float_as_uint(f);
  uint32_t r = u + 0x7fffu + ((u >> 16) & 1u);   // RNE
  return (uint16_t)(r >> 16);
}
__device__ __forceinline__ uint16_t f2h_bits(float f) {
  _Float16 h = (_Float16)f;
  return __builtin_bit_cast(uint16_t, h);
}
__device__ __forceinline__ float h2f_bits(uint16_t b) {
  return (float)__builtin_bit_cast(_Float16, b);
}
__device__ __forceinline__ float h2lo(uint32_t u) { return h2f_bits((uint16_t)u); }
__device__ __forceinline__ float h2hi(uint32_t u) { return h2f_bits((uint16_t)(u >> 16)); }

__device__ __forceinline__ float sigmoidf_fast(float x) {
  return 1.f / (1.f + __expf(-x));
}
__device__ __forceinline__ float tanhf_fast(float x) {
  float a = fabsf(x);
  float e = __expf(2.f * a);
  float t = 1.f - 2.f / (e + 1.f);
  return copysignf(t, x);
}

// ---------------- prep kernels ----------------

__global__ void k_cvt4(const float* __restrict__ src, uint16_t* __restrict__ dst, int n4) {
  int i = blockIdx.x * blockDim.x + threadIdx.x;
  if (i >= n4) return;
  const float4 v = ((const float4*)src)[i];
  ushort4 o;
  o.x = f2bf(v.x); o.y = f2bf(v.y); o.z = f2bf(v.z); o.w = f2bf(v.w);
  ((ushort4*)dst)[i] = o;
}

__global__ void k_zero_u32(uint32_t* __restrict__ p, int n) {
  int i = blockIdx.x * blockDim.x + threadIdx.x;
  if (i < n) p[i] = 0u;
}

// wcat[j][k] bf16, j = d*1024 + q*256 + g*64 + u  -> Wih_d row = g*256 + q*64 + u
__global__ void k_build_wcat2(const float* __restrict__ wf, const float* __restrict__ wb,
                              const float* __restrict__ biasf, const float* __restrict__ biasb,
                              uint16_t* __restrict__ wcat, float* __restrict__ biasp) {
  int id = blockIdx.x * 256 + threadIdx.x;    // 0 .. 524287
  int k = id & 255;
  int j = id >> 8;
  int d   = j >> 10;
  int q   = (j >> 8) & 3;
  int g   = (j >> 6) & 3;
  int u   = j & 63;
  const float* W = d ? wb : wf;
  const int row = g * 256 + q * 64 + u;
  wcat[id] = f2bf(W[row * 256 + k]);
  if (k == 0) biasp[j] = (d ? biasb : biasf)[row];
}

// wbfrag f16: id = ((((dq*4+w)*8 + kt)*4 + g)*64 + L)*8 + j8
// value = Whh_d[g*256 + q*64 + w*16 + (L&15)][kt*32 + (L>>4)*8 + j8]
__global__ void k_build_wbfrag(const float* __restrict__ whf, const float* __restrict__ whb,
                               uint16_t* __restrict__ wbfrag) {
  int id = blockIdx.x * 256 + threadIdx.x;    // 0 .. 524287
  int j8 = id & 7;
  int L  = (id >> 3) & 63;
  int g  = (id >> 9) & 3;
  int kt = (id >> 11) & 7;
  int w  = (id >> 14) & 3;
  int dq = id >> 16;              // 0..7
  int d = dq >> 2, q = dq & 3;
  const float* W = d ? whb : whf;
  const int row = g * 256 + q * 64 + w * 16 + (L & 15);
  const int k   = kt * 32 + (L >> 4) * 8 + j8;
  wbfrag[id] = f2h_bits(W[row * 256 + k]);
}

// ---------------- fused: recurrence WGs + next-chunk GEMM WGs ----------------
// blocks 0..31: bids with (bid&7)<2 are recurrence (d=bid&1, q=bid>>3) -> 8 WGs.
// blocks 32..2079: GEMM producing chunk c0g into xw_prod (recurrence-native layout).
// h exchange: hpub[2 parity][8 dq][64 unit][32 b]; h_s published to slot s&1.
// Parity-2 is race-free: a slot is overwritten (h_{s+2}) only after all sibling
// flags >= s+2, which implies every sibling already gathered h_s.
__global__ __launch_bounds__(256, 1) void k_fused(
    const float* __restrict__ x,          // [32][2048][256] f32
    const uint16_t* __restrict__ wcat,    // [2048][256] bf16
    const float* __restrict__ biasp,      // [2048]
    const uint16_t* __restrict__ wbfrag,  // MFMA B-frag packed Whh f16
    uint16_t* __restrict__ xw_prod,       // [8dq][128sl][4w][64L][32] f16
    const uint16_t* __restrict__ xw_cons,
    uint16_t* __restrict__ hcat,          // [B][T][512] f16
    uint16_t* __restrict__ hpub,          // [2][8dq][64 unit][32 b] f16
    float* __restrict__ cstate,           // [8dq][4w][64L][8] f32
    uint32_t* __restrict__ flags,         // [8dq * 16] u32
    int c0, int c0g, int do_lstm, int do_gemm) {
  __shared__ float4 lds_raw[1056];        // 16896 B: hbuf [32][264]f16 or Cs [64][65]f32
  const int tid = threadIdx.x;
  const int bid = blockIdx.x;

  if (bid < 32) {
    // ---------------- recurrence ----------------
    if ((bid & 7) >= 2 || !do_lstm) return;
    __builtin_amdgcn_s_setprio(1);

    uint16_t* hbuf = (uint16_t*)lds_raw;  // [32][HROW]
    const int d  = bid & 1;
    const int q  = bid >> 3;
    const int dq = d * 4 + q;
    const int lane = tid & 63;
    const int w    = tid >> 6;
    const int u15  = lane & 15;
    const int q4   = lane >> 4;

    // weight fragments -> registers (128 VGPRs)
    f16x8 wb[8][4];
    {
      const uint16_t* wsrc = wbfrag + (size_t)(dq * 4 + w) * 16384 + lane * 8;
#pragma unroll
      for (int kt = 0; kt < 8; ++kt)
#pragma unroll
        for (int g = 0; g < 4; ++g)
          wb[kt][g] = __builtin_bit_cast(f16x8, *(const short8*)(wsrc + (kt * 4 + g) * 512));
    }

    // c state
    float c[8];
    const size_t cbase = ((size_t)(dq * 4 + w) * 64 + lane) * 8;
#pragma unroll
    for (int i = 0; i < 8; ++i) c[i] = cstate[cbase + i];

    // fill hbuf from hpub slot 1 (chunk-boundary h always has odd parity; zeros for chunk 0)
    {
      const int ul = tid >> 3;
      const int b0 = (tid & 7) * 4;
#pragma unroll
      for (int qs = 0; qs < 4; ++qs) {
        const uint16_t* src = hpub + (8 + d * 4 + qs) * 2048;
#pragma unroll
        for (int rep = 0; rep < 2; ++rep) {
          const int ur = ul + rep * 32;
          unsigned long long v = __hip_atomic_load(
              (const unsigned long long*)(src + ur * 32 + b0),
              __ATOMIC_RELAXED, __HIP_MEMORY_SCOPE_AGENT);
          hbuf[(b0 + 0) * HROW + qs * 64 + ur] = (uint16_t)v;
          hbuf[(b0 + 1) * HROW + qs * 64 + ur] = (uint16_t)(v >> 16);
          hbuf[(b0 + 2) * HROW + qs * 64 + ur] = (uint16_t)(v >> 32);
          hbuf[(b0 + 3) * HROW + qs * 64 + ur] = (uint16_t)(v >> 48);
        }
      }
    }
    __syncthreads();

    const uint16_t* xbase = xw_cons + (size_t)dq * (128 * 4 * 64 * 32);
    const int ucol = q * 64 + w * 16 + u15;

    for (int sl = 0; sl < CHUNK; ++sl) {
      const int s = c0 + sl;
      const int t = d ? (TDIM - 1 - s) : s;
      const int par = s & 1;

      // prefetch gate pre-activations: 64 B contiguous per lane
      const uint16_t* xp = xbase + ((size_t)(sl * 4 + w) * 64 + lane) * 32;
      uint4 xq[4];
#pragma unroll
      for (int g = 0; g < 4; ++g) xq[g] = *(const uint4*)(xp + g * 8);

      // MFMA: gates = h @ Wslice
      f32x4 acc[4][2] = {};
#pragma unroll
      for (int kt = 0; kt < 8; ++kt) {
        const f16x8 a0 = __builtin_bit_cast(f16x8,
            *(const short8*)&hbuf[u15 * HROW + kt * 32 + q4 * 8]);
        const f16x8 a1 = __builtin_bit_cast(f16x8,
            *(const short8*)&hbuf[(16 + u15) * HROW + kt * 32 + q4 * 8]);
#pragma unroll
        for (int g = 0; g < 4; ++g) {
          acc[g][0] = __builtin_amdgcn_mfma_f32_16x16x32_f16(a0, wb[kt][g], acc[g][0], 0, 0, 0);
          acc[g][1] = __builtin_amdgcn_mfma_f32_16x16x32_f16(a1, wb[kt][g], acc[g][1], 0, 0, 0);
        }
      }
      __syncthreads();   // all LDS reads of h_{s-1} done

      // nonlinearity (unit = ucol fixed per lane; 8 batches)
      uint16_t hh[8];
#pragma unroll
      for (int m = 0; m < 2; ++m)
#pragma unroll
        for (int r = 0; r < 4; ++r) {
          const int e = m * 4 + r;
          const uint32_t x0 = ((const uint32_t*)&xq[0])[e >> 1];
          const uint32_t x1 = ((const uint32_t*)&xq[1])[e >> 1];
          const uint32_t x2 = ((const uint32_t*)&xq[2])[e >> 1];
          const uint32_t x3 = ((const uint32_t*)&xq[3])[e >> 1];
          const float gi = acc[0][m][r] + ((e & 1) ? h2hi(x0) : h2lo(x0));
          const float gf = acc[1][m][r] + ((e & 1) ? h2hi(x1) : h2lo(x1));
          const float gg = acc[2][m][r] + ((e & 1) ? h2hi(x2) : h2lo(x2));
          const float go = acc[3][m][r] + ((e & 1) ? h2hi(x3) : h2lo(x3));
          const float I = sigmoidf_fast(gi);
          const float F = sigmoidf_fast(gf);
          const float G = tanhf_fast(gg);
          const float O = sigmoidf_fast(go);
          c[e] = F * c[e] + I * G;
          const float h = O * tanhf_fast(c[e]);
          hh[e] = f2h_bits(h);
        }

      // own slice -> hbuf + hcat + hpub[parity]
#pragma unroll
      for (int e = 0; e < 8; ++e) {
        const int b = (e >> 2) * 16 + q4 * 4 + (e & 3);
        hbuf[b * HROW + ucol] = hh[e];
        hcat[((size_t)(b * TDIM + t)) * 512 + d * 256 + ucol] = hh[e];
      }
      {
        unsigned long long lo = (unsigned long long)hh[0] | ((unsigned long long)hh[1] << 16)
                              | ((unsigned long long)hh[2] << 32) | ((unsigned long long)hh[3] << 48);
        unsigned long long hi = (unsigned long long)hh[4] | ((unsigned long long)hh[5] << 16)
                              | ((unsigned long long)hh[6] << 32) | ((unsigned long long)hh[7] << 48);
        uint16_t* pb = hpub + (par * 8 + dq) * 2048 + (w * 16 + u15) * 32 + q4 * 4;
        __hip_atomic_store((unsigned long long*)(pb), lo,
                           __ATOMIC_RELAXED, __HIP_MEMORY_SCOPE_AGENT);
        __hip_atomic_store((unsigned long long*)(pb + 16), hi,
                           __ATOMIC_RELAXED, __HIP_MEMORY_SCOPE_AGENT);
      }
      asm volatile("s_waitcnt vmcnt(0)" ::: "memory");
      __syncthreads();   // every wave's publishes drained
      if (tid == 0)
        __hip_atomic_store(&flags[dq * 16], (uint32_t)(s + 1),
                           __ATOMIC_RELAXED, __HIP_MEMORY_SCOPE_AGENT);

      if (sl + 1 < CHUNK) {
        if (tid < 3) {
          const int qo = tid + (tid >= q ? 1 : 0);
          const uint32_t tgt = (uint32_t)(s + 1);
          while (__hip_atomic_load(&flags[(d * 4 + qo) * 16],
                                   __ATOMIC_RELAXED, __HIP_MEMORY_SCOPE_AGENT) < tgt)
            __builtin_amdgcn_s_sleep(1);
        }
        __syncthreads();
        // gather sibling slices from hpub[parity of step s]
        const int ul = tid >> 3;
        const int b0 = (tid & 7) * 4;
#pragma unroll
        for (int qs = 0; qs < 4; ++qs) {
          if (qs == q) continue;
          const uint16_t* src = hpub + (par * 8 + d * 4 + qs) * 2048;
#pragma unroll
          for (int rep = 0; rep < 2; ++rep) {
            const int ur = ul + rep * 32;
            unsigned long long v = __hip_atomic_load(
                (const unsigned long long*)(src + ur * 32 + b0),
                __ATOMIC_RELAXED, __HIP_MEMORY_SCOPE_AGENT);
            hbuf[(b0 + 0) * HROW + qs * 64 + ur] = (uint16_t)v;
            hbuf[(b0 + 1) * HROW + qs * 64 + ur] = (uint16_t)(v >> 16);
            hbuf[(b0 + 2) * HROW + qs * 64 + ur] = (uint16_t)(v >> 32);
            hbuf[(b0 + 3) * HROW + qs * 64 + ur] = (uint16_t)(v >> 48);
          }
        }
        __syncthreads();
      }
    }
    // save c state (h persists via hpub slot 1)
#pragma unroll
    for (int i = 0; i < 8; ++i) cstate[cbase + i] = c[i];
    return;
  }

  // ---------------- GEMM: produce chunk c0g ----------------
  if (!do_gemm) return;
  float* Cs = (float*)lds_raw;            // [64][65]
  const int gid = bid - 32;               // 0..2047
  const int mt = gid >> 5;                // 64 row tiles (2 sl each)
  const int nt = gid & 31;                // 32 col tiles: nt = d*16 + q*4 + g
  const int dq_t = nt >> 2;               // d*4 + q
  const int d_t  = nt >> 4;               // FIX (was nt>>3): direction is bit 4 of nt
  const int g_t  = nt & 3;
  const int wid = tid >> 6;
  const int lane = tid & 63;
  const int l15 = lane & 15;
  const int lg  = lane >> 4;

  const int row = mt * 64 + wid * 16 + l15;
  const int sl_g = row >> 5;
  const int brow = row & 31;
  const int t = d_t ? (TDIM - 1 - (c0g + sl_g)) : (c0g + sl_g);
  const float*    Abase = x + ((size_t)(brow * TDIM + t)) * 256 + lg * 8;
  const uint16_t* Bbase = wcat + ((size_t)(nt * 64 + l15)) * 256 + lg * 8;

  f32x4 acc[4] = {};
#pragma unroll
  for (int ks = 0; ks < 8; ++ks) {
    const float4 f0 = *(const float4*)(Abase + ks * 32);
    const float4 f1 = *(const float4*)(Abase + ks * 32 + 4);
    short8 a;
    a[0] = (short)f2bf(f0.x); a[1] = (short)f2bf(f0.y);
    a[2] = (short)f2bf(f0.z); a[3] = (short)f2bf(f0.w);
    a[4] = (short)f2bf(f1.x); a[5] = (short)f2bf(f1.y);
    a[6] = (short)f2bf(f1.z); a[7] = (short)f2bf(f1.w);
#pragma unroll
    for (int ni = 0; ni < 4; ++ni) {
      const short8 bfr = *(const short8*)(Bbase + ni * 16 * 256 + ks * 32);
      acc[ni] = __builtin_amdgcn_mfma_f32_16x16x32_bf16(a, bfr, acc[ni], 0, 0, 0);
    }
  }
#pragma unroll
  for (int ni = 0; ni < 4; ++ni) {
    const float bv = biasp[nt * 64 + ni * 16 + l15];
    const int col = ni * 16 + l15;
#pragma unroll
    for (int r = 0; r < 4; ++r)
      Cs[(wid * 16 + lg * 4 + r) * 65 + col] = acc[ni][r] + bv;
  }
  __syncthreads();

  // scatter into recurrence-native layout
  const int u   = tid & 63;
  const int m   = (tid >> 6) & 1;
  const int slh = tid >> 7;
  const int sl  = mt * 2 + slh;
  const int w_u = u >> 4, u15u = u & 15;
#pragma unroll
  for (int q4 = 0; q4 < 4; ++q4) {
    uint16_t pk[4];
#pragma unroll
    for (int r = 0; r < 4; ++r)
      pk[r] = f2h_bits(Cs[(slh * 32 + m * 16 + q4 * 4 + r) * 65 + u]);
    const size_t off = (((size_t)(dq_t * 128 + sl) * 4 + w_u) * 64 + (q4 * 16 + u15u)) * 32
                       + g_t * 8 + m * 4;
    uint2 v;
    v.x = (uint32_t)pk[0] | ((uint32_t)pk[1] << 16);
    v.y = (uint32_t)pk[2] | ((uint32_t)pk[3] << 16);
    *(uint2*)(xw_prod + off) = v;
  }
}

// ---------------- LayerNorm + FC (MFMA) ----------------
__global__ __launch_bounds__(256) void k_lnfc2(
    const uint16_t* __restrict__ hcat,
    const float* __restrict__ lng, const float* __restrict__ lnb,
    const uint16_t* __restrict__ fcwb,  // [256][512] bf16
    const float* __restrict__ fcb,
    float* __restrict__ out) {
  __shared__ uint16_t lnh[64 * 520];
  __shared__ float slng[512], slnb[512];

  const int tid = threadIdx.x;
  const size_t bt0 = (size_t)blockIdx.x * 64;

  slng[tid] = lng[tid]; slng[tid + 256] = lng[tid + 256];
  slnb[tid] = lnb[tid]; slnb[tid + 256] = lnb[tid + 256];

  const int row = tid >> 2;
  const int part = tid & 3;
  const uint16_t* hrow = hcat + (bt0 + row) * 512;
  float s = 0.f, s2 = 0.f;
#pragma unroll
  for (int i = 0; i < 16; ++i) {
    const uint4 u = *(const uint4*)(hrow + (i * 4 + part) * 8);
    const float f0 = h2lo(u.x), f1 = h2hi(u.x), f2 = h2lo(u.y), f3 = h2hi(u.y);
    const float f4 = h2lo(u.z), f5 = h2hi(u.z), f6 = h2lo(u.w), f7 = h2hi(u.w);
    s  += ((f0 + f1) + (f2 + f3)) + ((f4 + f5) + (f6 + f7));
    s2 += ((f0*f0 + f1*f1) + (f2*f2 + f3*f3)) + ((f4*f4 + f5*f5) + (f6*f6 + f7*f7));
  }
  s  += __shfl_xor(s, 1, 64);  s  += __shfl_xor(s, 2, 64);
  s2 += __shfl_xor(s2, 1, 64); s2 += __shfl_xor(s2, 2, 64);
  const float mu = s * (1.f / 512.f);
  const float var = s2 * (1.f / 512.f) - mu * mu;
  const float rs = rsqrtf(var + 1e-5f);
  __syncthreads();

#pragma unroll
  for (int i = 0; i < 16; ++i) {
    const int kb = (i * 4 + part) * 8;
    const uint4 u = *(const uint4*)(hrow + kb);
    uint16_t tmp[8] __attribute__((aligned(16)));
    const float f[8] = { h2lo(u.x), h2hi(u.x), h2lo(u.y), h2hi(u.y),
                         h2lo(u.z), h2hi(u.z), h2lo(u.w), h2hi(u.w) };
#pragma unroll
    for (int e = 0; e < 8; ++e)
      tmp[e] = f2bf((f[e] - mu) * rs * slng[kb + e] + slnb[kb + e]);
    *(short8*)&lnh[row * 520 + kb] = *(const short8*)tmp;
  }
  __syncthreads();

  const int w = tid >> 6;
  const int lane = tid & 63;
  const int l15 = lane & 15;
  const int lg = lane >> 4;
  f32x4 acc[4][4] = {};
#pragma unroll
  for (int nf = 0; nf < 4; ++nf) {
    const uint16_t* bb = fcwb + (size_t)(w * 64 + nf * 16 + l15) * 512 + lg * 8;
#pragma unroll 4
    for (int k0 = 0; k0 < 16; ++k0) {
      const short8 bfr = *(const short8*)(bb + k0 * 32);
#pragma unroll
      for (int mf = 0; mf < 4; ++mf) {
        const short8 afr = *(const short8*)&lnh[(mf * 16 + l15) * 520 + k0 * 32 + lg * 8];
        acc[mf][nf] = __builtin_amdgcn_mfma_f32_16x16x32_bf16(afr, bfr, acc[mf][nf], 0, 0, 0);
      }
    }
  }
#pragma unroll
  for (int nf = 0; nf < 4; ++nf) {
    const int col = w * 64 + nf * 16 + l15;
    const float fv = fcb[col];
#pragma unroll
    for (int mf = 0; mf < 4; ++mf)
#pragma unroll
      for (int r = 0; r < 4; ++r)
        out[(bt0 + mf * 16 + lg * 4 + r) * 256 + col] = acc[mf][nf][r] + fv;
  }
}

// ---------------- launcher ----------------

extern "C" void kernel_launch(void* const* d_in, const int* in_sizes, int n_in,
                              void* d_out, int out_size, void* d_ws, size_t ws_size,
                              hipStream_t stream) {
  const float* x    = (const float*)d_in[0];
  const float* Wihf = (const float*)d_in[1];
  const float* Whhf = (const float*)d_in[2];
  const float* bf_  = (const float*)d_in[3];
  const float* Wihb = (const float*)d_in[4];
  const float* Whhb = (const float*)d_in[5];
  const float* bb_  = (const float*)d_in[6];
  const float* lng  = (const float*)d_in[7];
  const float* lnb  = (const float*)d_in[8];
  const float* fcW  = (const float*)d_in[9];
  const float* fcb  = (const float*)d_in[10];
  float* out = (float*)d_out;

  char* ws = (char*)d_ws;
  size_t off = 0;
  uint16_t* wcat   = (uint16_t*)(ws + off); off += (size_t)2048 * 256 * 2;         // 1.0 MB
  float*    biasp  = (float*)(ws + off);    off += (size_t)2048 * 4;               // 8 KB
  uint16_t* wbfrag = (uint16_t*)(ws + off); off += (size_t)524288 * 2;             // 1.0 MB
  uint16_t* fcwb   = (uint16_t*)(ws + off); off += (size_t)256 * 512 * 2;          // 0.26 MB
  uint32_t* flags  = (uint32_t*)(ws + off); off += 1024;                           // 1 KB
  uint16_t* hpub   = (uint16_t*)(ws + off); off += (size_t)2 * 8 * 2048 * 2;       // 64 KB
  float*    cstate = (float*)(ws + off);    off += (size_t)8 * 4 * 64 * 8 * 4;     // 64 KB
  uint16_t* xw0    = (uint16_t*)(ws + off); off += (size_t)8388608 * 2;            // 16.8 MB
  uint16_t* xw1    = (uint16_t*)(ws + off); off += (size_t)8388608 * 2;            // 16.8 MB
  uint16_t* hcat   = (uint16_t*)(ws + off); off += (size_t)65536 * 512 * 2;        // 67 MB
  (void)ws_size; (void)in_sizes; (void)n_in; (void)out_size;
  // total ~103 MB

  // prep (runs every call: flags/hpub/cstate re-zeroed for graph replay determinism)
  k_cvt4<<<128, 256, 0, stream>>>(fcW, fcwb, 131072 / 4);
  k_build_wcat2<<<2048, 256, 0, stream>>>(Wihf, Wihb, bf_, bb_, wcat, biasp);
  k_build_wbfrag<<<2048, 256, 0, stream>>>(Whhf, Whhb, wbfrag);
  // flags(1KB) + hpub(64KB) + cstate(64KB) contiguous = 129 KB = 33024 u32
  k_zero_u32<<<129, 256, 0, stream>>>(flags, 33024);

  // prologue: GEMM chunk 0 -> xw0
  k_fused<<<32 + 2048, 256, 0, stream>>>(x, wcat, biasp, wbfrag, xw0, xw1,
                                         hcat, hpub, cstate, flags, 0, 0, 0, 1);

  for (int ck = 0; ck < NCHUNK; ++ck) {
    uint16_t* cons = (ck & 1) ? xw1 : xw0;
    uint16_t* prod = (ck & 1) ? xw0 : xw1;
    const int dg = (ck < NCHUNK - 1) ? 1 : 0;
    const int grid = dg ? (32 + 2048) : 32;
    k_fused<<<grid, 256, 0, stream>>>(x, wcat, biasp, wbfrag, prod, cons,
                                      hcat, hpub, cstate, flags,
                                      ck * CHUNK, (ck + 1) * CHUNK, 1, dg);
  }

  k_lnfc2<<<1024, 256, 0, stream>>>(hcat, lng, lnb, fcwb, fcb, out);
}

// Round 8
// 9837.680 us; speedup vs baseline: 1.1540x; 1.1495x over previous
//
#include <hip/hip_runtime.h>
#include <cstdint>
#include <cstddef>

// Problem dims
#define BDIM 32
#define TDIM 2048
#define IDIM 256
#define HDIM 256
#define CHUNK 128
#define NCHUNK (TDIM / CHUNK)

using short8 = __attribute__((ext_vector_type(8))) short;
using f32x4  = __attribute__((ext_vector_type(4))) float;
typedef _Float16 f16x8 __attribute__((ext_vector_type(8)));

__device__ __forceinline__ uint16_t f2bf(float f) {
  uint32_t u = __float_as_uint(f);
  uint32_t r = u + 0x7fffu + ((u >> 16) & 1u);   // RNE
  return (uint16_t)(r >> 16);
}
__device__ __forceinline__ uint16_t f2h_bits(float f) {
  _Float16 h = (_Float16)f;
  return __builtin_bit_cast(uint16_t, h);
}
__device__ __forceinline__ float h2lo(uint32_t u) {
  return (float)__builtin_bit_cast(_Float16, (uint16_t)u);
}
__device__ __forceinline__ float h2hi(uint32_t u) {
  return (float)__builtin_bit_cast(_Float16, (uint16_t)(u >> 16));
}
__device__ __forceinline__ float sigmoidf_fast(float x) {
  return 1.f / (1.f + __expf(-x));
}
__device__ __forceinline__ float tanhf_fast(float x) {
  float a = fabsf(x);
  float e = __expf(2.f * a);
  float t = 1.f - 2.f / (e + 1.f);
  return copysignf(t, x);
}

// ---------------- prep kernels ----------------

__global__ void k_cvt4(const float* __restrict__ src, uint16_t* __restrict__ dst, int n4) {
  int i = blockIdx.x * blockDim.x + threadIdx.x;
  if (i >= n4) return;
  const float4 v = ((const float4*)src)[i];
  ushort4 o;
  o.x = f2bf(v.x); o.y = f2bf(v.y); o.z = f2bf(v.z); o.w = f2bf(v.w);
  ((ushort4*)dst)[i] = o;
}

__global__ void k_zero_u32(uint32_t* __restrict__ p, int n) {
  int i = blockIdx.x * blockDim.x + threadIdx.x;
  if (i < n) p[i] = 0u;
}

// wcat[j][k] bf16: j = d*1024 + U*4 + g  -> Wih_d row = g*256 + U
__global__ void k_build_wcat3(const float* __restrict__ wf, const float* __restrict__ wb,
                              const float* __restrict__ biasf, const float* __restrict__ biasb,
                              uint16_t* __restrict__ wcat, float* __restrict__ biasp) {
  int id = blockIdx.x * 256 + threadIdx.x;    // 0 .. 524287
  int k = id & 255;
  int j = id >> 8;
  int d  = j >> 10;
  int jj = j & 1023;
  int U  = jj >> 2;
  int g  = jj & 3;
  const float* W = d ? wb : wf;
  const int row = g * 256 + U;
  wcat[id] = f2bf(W[row * 256 + k]);
  if (k == 0) biasp[j] = (d ? biasb : biasf)[row];
}

// wbf f16 MFMA B-frags: id = (((d*8+w)*8 + kt)*8 + nf)*512 + L*8 + j8
// g = nf>>1, n2 = nf&1, u = w*32 + n2*16 + (L&15), k = kt*32 + (L>>4)*8 + j8
// value = Whh_d[g*256 + u][k]
__global__ void k_build_wbf(const float* __restrict__ whf, const float* __restrict__ whb,
                            uint16_t* __restrict__ wbf) {
  int id = blockIdx.x * 256 + threadIdx.x;    // 0 .. 524287
  int j8 = id & 7;
  int L  = (id >> 3) & 63;
  int nf = (id >> 9) & 7;
  int kt = (id >> 12) & 7;
  int w  = (id >> 15) & 7;
  int d  = (id >> 18) & 1;
  int g = nf >> 1, n2 = nf & 1;
  int u = w * 32 + n2 * 16 + (L & 15);
  int k = kt * 32 + (L >> 4) * 8 + j8;
  const float* W = d ? whb : whf;
  wbf[id] = f2h_bits(W[(g * 256 + u) * 256 + k]);
}

// ---------------- fused: 4 recurrence WGs + GEMM WGs ----------------
// blocks 0..3: recurrence. bid = bh*2 + d (d = bid&1, bh = bid>>1).
//   Each WG: 16 batches x one direction, full 256 hidden units. 512 thr = 8 waves.
//   Weights: kt0-3 in VGPR B-frags, kt4 in LDS (staged once), kt5-7 streamed from L2
//   each step. h in LDS MFMA-A-fragment layout, double-buffered; 1 barrier/step.
//   NO cross-WG communication.
// blocks 4..1027: GEMM producing chunk c0g into xw_prod.
//   xw layout per (bh*2+d): [sl 128][tid 512][32 f16], thread-coalesced 64B reads.
__global__ __launch_bounds__(512, 1) void k_fused(
    const float* __restrict__ x,          // [32][2048][256] f32
    const uint16_t* __restrict__ wcat,    // [2048][256] bf16
    const float* __restrict__ biasp,      // [2048]
    const uint16_t* __restrict__ wbf,     // MFMA B-frag Whh f16
    uint16_t* __restrict__ xw_prod,
    const uint16_t* __restrict__ xw_cons,
    uint16_t* __restrict__ hcat,          // [B][T][512] f16
    uint16_t* __restrict__ hstate,        // [4][4096] f16
    float* __restrict__ cstate,           // [4][512][8] f32
    int c0, int c0g, int do_lstm, int do_gemm) {
  __shared__ char smem[86016];            // rec: wlds 64KB + ha 16KB; gemm: Cs 33KB
  const int tid = threadIdx.x;
  const int bid = blockIdx.x;

  if (bid < 4) {
    // ---------------- recurrence ----------------
    if (!do_lstm) return;
    __builtin_amdgcn_s_setprio(1);

    uint16_t* wlds = (uint16_t*)smem;                 // [8 w][8 nf][512] (kt4)
    uint16_t* ha   = (uint16_t*)(smem + 65536);       // [2][4096]

    const int d  = bid & 1;
    const int bh = bid >> 1;
    const int w    = tid >> 6;
    const int L    = tid & 63;
    const int l15  = L & 15;
    const int q4   = L >> 4;

    const uint16_t* wsb = wbf + (size_t)(d * 8 + w) * (8 * 8 * 512);

    // kt0-3 weight fragments -> 128 VGPRs
    f16x8 wreg[4][8];
#pragma unroll
    for (int kt = 0; kt < 4; ++kt)
#pragma unroll
      for (int nf = 0; nf < 8; ++nf)
        wreg[kt][nf] = __builtin_bit_cast(f16x8,
            *(const short8*)(wsb + (kt * 8 + nf) * 512 + L * 8));

    // kt4 -> LDS (each wave stages its own slice)
#pragma unroll
    for (int nf = 0; nf < 8; ++nf)
      *(short8*)&wlds[(w * 8 + nf) * 512 + L * 8] =
          *(const short8*)(wsb + (4 * 8 + nf) * 512 + L * 8);

    // h state -> ha[0]
    *(short8*)&ha[tid * 8] = *(const short8*)(hstate + bid * 4096 + tid * 8);

    float c[8];
#pragma unroll
    for (int i = 0; i < 8; ++i) c[i] = cstate[(bid * 512 + tid) * 8 + i];
    __syncthreads();

    const uint16_t* xwd = xw_cons + (size_t)bid * (CHUNK * 512 * 32);

    for (int sl = 0; sl < CHUNK; ++sl) {
      const int s = c0 + sl;
      const int t = d ? (TDIM - 1 - s) : s;
      const int rd = sl & 1;
      const uint16_t* harow = &ha[rd * 4096];
      uint16_t* hawr = &ha[(rd ^ 1) * 4096];
      const uint16_t* xp = xwd + ((size_t)sl * 512 + tid) * 32;

#pragma unroll
      for (int p = 0; p < 2; ++p) {
        asm volatile("" ::: "memory");   // keep streamed weight loads inside the loop
        // issue streamed weights kt5-7 (constant data, L2-resident) + this phase's xq
        f16x8 sb5[4], sb6[4], sb7[4];
#pragma unroll
        for (int g = 0; g < 4; ++g)
          sb5[g] = __builtin_bit_cast(f16x8,
              *(const short8*)(wsb + (5 * 8 + g * 2 + p) * 512 + L * 8));
#pragma unroll
        for (int g = 0; g < 4; ++g)
          sb6[g] = __builtin_bit_cast(f16x8,
              *(const short8*)(wsb + (6 * 8 + g * 2 + p) * 512 + L * 8));
#pragma unroll
        for (int g = 0; g < 4; ++g)
          sb7[g] = __builtin_bit_cast(f16x8,
              *(const short8*)(wsb + (7 * 8 + g * 2 + p) * 512 + L * 8));
        const uint4 xqa = *(const uint4*)(xp + p * 16);
        const uint4 xqb = *(const uint4*)(xp + p * 16 + 8);

        f32x4 acc[4] = {};
#pragma unroll
        for (int kt = 0; kt < 4; ++kt) {
          const f16x8 af = __builtin_bit_cast(f16x8,
              *(const short8*)&harow[kt * 512 + L * 8]);
#pragma unroll
          for (int g = 0; g < 4; ++g)
            acc[g] = __builtin_amdgcn_mfma_f32_16x16x32_f16(af, wreg[kt][g * 2 + p], acc[g], 0, 0, 0);
        }
        {
          const f16x8 af = __builtin_bit_cast(f16x8,
              *(const short8*)&harow[4 * 512 + L * 8]);
#pragma unroll
          for (int g = 0; g < 4; ++g) {
            const f16x8 bw = __builtin_bit_cast(f16x8,
                *(const short8*)&wlds[(w * 8 + g * 2 + p) * 512 + L * 8]);
            acc[g] = __builtin_amdgcn_mfma_f32_16x16x32_f16(af, bw, acc[g], 0, 0, 0);
          }
        }
        {
          const f16x8 af = __builtin_bit_cast(f16x8,
              *(const short8*)&harow[5 * 512 + L * 8]);
#pragma unroll
          for (int g = 0; g < 4; ++g)
            acc[g] = __builtin_amdgcn_mfma_f32_16x16x32_f16(af, sb5[g], acc[g], 0, 0, 0);
        }
        {
          const f16x8 af = __builtin_bit_cast(f16x8,
              *(const short8*)&harow[6 * 512 + L * 8]);
#pragma unroll
          for (int g = 0; g < 4; ++g)
            acc[g] = __builtin_amdgcn_mfma_f32_16x16x32_f16(af, sb6[g], acc[g], 0, 0, 0);
        }
        {
          const f16x8 af = __builtin_bit_cast(f16x8,
              *(const short8*)&harow[7 * 512 + L * 8]);
#pragma unroll
          for (int g = 0; g < 4; ++g)
            acc[g] = __builtin_amdgcn_mfma_f32_16x16x32_f16(af, sb7[g], acc[g], 0, 0, 0);
        }

        // nonlinearity: 4 (b,u) quads; u = w*32 + p*16 + l15, b = q4*4 + r
        const uint32_t xw32[8] = { xqa.x, xqa.y, xqa.z, xqa.w, xqb.x, xqb.y, xqb.z, xqb.w };
        const int u = w * 32 + p * 16 + l15;
        const int lpbase = 16 * ((p * 2 + (l15 >> 3)) & 3);
#pragma unroll
        for (int r = 0; r < 4; ++r) {
          const uint32_t w01 = xw32[r * 2];
          const uint32_t w23 = xw32[r * 2 + 1];
          const float gi = acc[0][r] + h2lo(w01);
          const float gf = acc[1][r] + h2hi(w01);
          const float gg = acc[2][r] + h2lo(w23);
          const float go = acc[3][r] + h2hi(w23);
          const float I = sigmoidf_fast(gi);
          const float F = sigmoidf_fast(gf);
          const float G = tanhf_fast(gg);
          const float O = sigmoidf_fast(go);
          float& cc = c[p * 4 + r];
          cc = F * cc + I * G;
          const float h = O * tanhf_fast(cc);
          const uint16_t hb = f2h_bits(h);
          const int b = q4 * 4 + r;
          hawr[w * 512 + (b + lpbase) * 8 + (l15 & 7)] = hb;
          hcat[((size_t)((bh * 16 + b) * TDIM + t)) * 512 + d * 256 + u] = hb;
        }
      }
      __syncthreads();
    }

    // save state (CHUNK even -> final h in ha[0])
    *(short8*)(hstate + bid * 4096 + tid * 8) = *(const short8*)&ha[tid * 8];
#pragma unroll
    for (int i = 0; i < 8; ++i) cstate[(bid * 512 + tid) * 8 + i] = c[i];
    return;
  }

  // ---------------- GEMM: produce chunk c0g ----------------
  if (!do_gemm) return;
  float* Cs = (float*)smem;               // [32][260]
  const int gid = bid - 4;                // 0..1023
  const int mt  = gid >> 3;               // 128 m-tiles = sl
  const int nt8 = gid & 7;                // 8 n-tiles of 256 cols
  const int d  = nt8 >> 2;
  const int dn = nt8 & 3;
  const int wv = tid >> 6;
  const int mh = wv & 1;                  // = bh
  const int nq = wv >> 1;
  const int L = tid & 63;
  const int l15 = L & 15;
  const int lg  = L >> 4;

  const int jbase = d * 1024 + dn * 256 + nq * 64;
  const int t = d ? (TDIM - 1 - (c0g + mt)) : (c0g + mt);
  const float* Abase = x + ((size_t)((mh * 16 + l15) * TDIM + t)) * 256 + lg * 8;

  f32x4 acc[4] = {};
#pragma unroll
  for (int ks = 0; ks < 8; ++ks) {
    const float4 f0 = *(const float4*)(Abase + ks * 32);
    const float4 f1 = *(const float4*)(Abase + ks * 32 + 4);
    short8 a;
    a[0] = (short)f2bf(f0.x); a[1] = (short)f2bf(f0.y);
    a[2] = (short)f2bf(f0.z); a[3] = (short)f2bf(f0.w);
    a[4] = (short)f2bf(f1.x); a[5] = (short)f2bf(f1.y);
    a[6] = (short)f2bf(f1.z); a[7] = (short)f2bf(f1.w);
#pragma unroll
    for (int nf = 0; nf < 4; ++nf) {
      const short8 bfr = *(const short8*)(wcat + (size_t)(jbase + nf * 16 + l15) * 256 + ks * 32 + lg * 8);
      acc[nf] = __builtin_amdgcn_mfma_f32_16x16x32_bf16(a, bfr, acc[nf], 0, 0, 0);
    }
  }
#pragma unroll
  for (int nf = 0; nf < 4; ++nf) {
    const float bv = biasp[jbase + nf * 16 + l15];
    const int col = nq * 64 + nf * 16 + l15;
#pragma unroll
    for (int r = 0; r < 4; ++r)
      Cs[(mh * 16 + lg * 4 + r) * 260 + col] = acc[nf][r] + bv;
  }
  __syncthreads();

  // scatter into recurrence-native layout: [bh*2+d][sl][tid2][32 f16]
#pragma unroll
  for (int i = 0; i < 4; ++i) {
    const int o = tid * 4 + i;            // 0..2047
    const int rr = o >> 6;                // batch row 0..31
    const int uloc = o & 63;
    const float f0 = Cs[rr * 260 + uloc * 4 + 0];
    const float f1 = Cs[rr * 260 + uloc * 4 + 1];
    const float f2 = Cs[rr * 260 + uloc * 4 + 2];
    const float f3 = Cs[rr * 260 + uloc * 4 + 3];
    const int U = dn * 64 + uloc;
    const int bh_o = rr >> 4;
    const int b16 = rr & 15;
    const int tid2 = (U >> 5) * 64 + (b16 >> 2) * 16 + (U & 15);
    const int e0 = (((U >> 4) & 1) * 4 + (b16 & 3)) * 4;
    uint2 v;
    v.x = (uint32_t)f2h_bits(f0) | ((uint32_t)f2h_bits(f1) << 16);
    v.y = (uint32_t)f2h_bits(f2) | ((uint32_t)f2h_bits(f3) << 16);
    *(uint2*)(xw_prod + ((size_t)(bh_o * 2 + d) * CHUNK + mt) * (512 * 32) + tid2 * 32 + e0) = v;
  }
}

// ---------------- LayerNorm + FC (MFMA) ----------------
__global__ __launch_bounds__(256) void k_lnfc2(
    const uint16_t* __restrict__ hcat,
    const float* __restrict__ lng, const float* __restrict__ lnb,
    const uint16_t* __restrict__ fcwb,  // [256][512] bf16
    const float* __restrict__ fcb,
    float* __restrict__ out) {
  __shared__ uint16_t lnh[64 * 520];
  __shared__ float slng[512], slnb[512];

  const int tid = threadIdx.x;
  const size_t bt0 = (size_t)blockIdx.x * 64;

  slng[tid] = lng[tid]; slng[tid + 256] = lng[tid + 256];
  slnb[tid] = lnb[tid]; slnb[tid + 256] = lnb[tid + 256];

  const int row = tid >> 2;
  const int part = tid & 3;
  const uint16_t* hrow = hcat + (bt0 + row) * 512;
  float s = 0.f, s2 = 0.f;
#pragma unroll
  for (int i = 0; i < 16; ++i) {
    const uint4 u = *(const uint4*)(hrow + (i * 4 + part) * 8);
    const float f0 = h2lo(u.x), f1 = h2hi(u.x), f2 = h2lo(u.y), f3 = h2hi(u.y);
    const float f4 = h2lo(u.z), f5 = h2hi(u.z), f6 = h2lo(u.w), f7 = h2hi(u.w);
    s  += ((f0 + f1) + (f2 + f3)) + ((f4 + f5) + (f6 + f7));
    s2 += ((f0*f0 + f1*f1) + (f2*f2 + f3*f3)) + ((f4*f4 + f5*f5) + (f6*f6 + f7*f7));
  }
  s  += __shfl_xor(s, 1, 64);  s  += __shfl_xor(s, 2, 64);
  s2 += __shfl_xor(s2, 1, 64); s2 += __shfl_xor(s2, 2, 64);
  const float mu = s * (1.f / 512.f);
  const float var = s2 * (1.f / 512.f) - mu * mu;
  const float rs = rsqrtf(var + 1e-5f);
  __syncthreads();

#pragma unroll
  for (int i = 0; i < 16; ++i) {
    const int kb = (i * 4 + part) * 8;
    const uint4 u = *(const uint4*)(hrow + kb);
    uint16_t tmp[8] __attribute__((aligned(16)));
    const float f[8] = { h2lo(u.x), h2hi(u.x), h2lo(u.y), h2hi(u.y),
                         h2lo(u.z), h2hi(u.z), h2lo(u.w), h2hi(u.w) };
#pragma unroll
    for (int e = 0; e < 8; ++e)
      tmp[e] = f2bf((f[e] - mu) * rs * slng[kb + e] + slnb[kb + e]);
    *(short8*)&lnh[row * 520 + kb] = *(const short8*)tmp;
  }
  __syncthreads();

  const int w = tid >> 6;
  const int lane = tid & 63;
  const int l15 = lane & 15;
  const int lg = lane >> 4;
  f32x4 acc[4][4] = {};
#pragma unroll
  for (int nf = 0; nf < 4; ++nf) {
    const uint16_t* bb = fcwb + (size_t)(w * 64 + nf * 16 + l15) * 512 + lg * 8;
#pragma unroll 4
    for (int k0 = 0; k0 < 16; ++k0) {
      const short8 bfr = *(const short8*)(bb + k0 * 32);
#pragma unroll
      for (int mf = 0; mf < 4; ++mf) {
        const short8 afr = *(const short8*)&lnh[(mf * 16 + l15) * 520 + k0 * 32 + lg * 8];
        acc[mf][nf] = __builtin_amdgcn_mfma_f32_16x16x32_bf16(afr, bfr, acc[mf][nf], 0, 0, 0);
      }
    }
  }
#pragma unroll
  for (int nf = 0; nf < 4; ++nf) {
    const int col = w * 64 + nf * 16 + l15;
    const float fv = fcb[col];
#pragma unroll
    for (int mf = 0; mf < 4; ++mf)
#pragma unroll
      for (int r = 0; r < 4; ++r)
        out[(bt0 + mf * 16 + lg * 4 + r) * 256 + col] = acc[mf][nf][r] + fv;
  }
}

// ---------------- launcher ----------------

extern "C" void kernel_launch(void* const* d_in, const int* in_sizes, int n_in,
                              void* d_out, int out_size, void* d_ws, size_t ws_size,
                              hipStream_t stream) {
  const float* x    = (const float*)d_in[0];
  const float* Wihf = (const float*)d_in[1];
  const float* Whhf = (const float*)d_in[2];
  const float* bf_  = (const float*)d_in[3];
  const float* Wihb = (const float*)d_in[4];
  const float* Whhb = (const float*)d_in[5];
  const float* bb_  = (const float*)d_in[6];
  const float* lng  = (const float*)d_in[7];
  const float* lnb  = (const float*)d_in[8];
  const float* fcW  = (const float*)d_in[9];
  const float* fcb  = (const float*)d_in[10];
  float* out = (float*)d_out;

  char* ws = (char*)d_ws;
  size_t off = 0;
  uint16_t* wcat   = (uint16_t*)(ws + off); off += (size_t)2048 * 256 * 2;            // 1.0 MB
  float*    biasp  = (float*)(ws + off);    off += (size_t)2048 * 4;                  // 8 KB
  uint16_t* wbf    = (uint16_t*)(ws + off); off += (size_t)524288 * 2;                // 1.0 MB
  uint16_t* fcwb   = (uint16_t*)(ws + off); off += (size_t)256 * 512 * 2;             // 0.26 MB
  float*    cstate = (float*)(ws + off);    off += (size_t)4 * 512 * 8 * 4;           // 64 KB
  uint16_t* hstate = (uint16_t*)(ws + off); off += (size_t)4 * 4096 * 2;              // 32 KB
  uint16_t* xw0    = (uint16_t*)(ws + off); off += (size_t)4 * CHUNK * 512 * 32 * 2;  // 16.8 MB
  uint16_t* xw1    = (uint16_t*)(ws + off); off += (size_t)4 * CHUNK * 512 * 32 * 2;  // 16.8 MB
  uint16_t* hcat   = (uint16_t*)(ws + off); off += (size_t)65536 * 512 * 2;           // 67 MB
  (void)ws_size; (void)in_sizes; (void)n_in; (void)out_size;
  // total ~103 MB

  // prep (each call: cstate/hstate re-zeroed for graph-replay determinism)
  k_cvt4<<<128, 256, 0, stream>>>(fcW, fcwb, 131072 / 4);
  k_build_wcat3<<<2048, 256, 0, stream>>>(Wihf, Wihb, bf_, bb_, wcat, biasp);
  k_build_wbf<<<2048, 256, 0, stream>>>(Whhf, Whhb, wbf);
  // cstate(64KB)+hstate(32KB) contiguous = 24576 u32
  k_zero_u32<<<96, 256, 0, stream>>>((uint32_t*)cstate, 24576);

  // prologue: GEMM chunk 0 -> xw0
  k_fused<<<4 + 1024, 512, 0, stream>>>(x, wcat, biasp, wbf, xw0, xw1,
                                        hcat, hstate, cstate, 0, 0, 0, 1);

  for (int ck = 0; ck < NCHUNK; ++ck) {
    uint16_t* cons = (ck & 1) ? xw1 : xw0;
    uint16_t* prod = (ck & 1) ? xw0 : xw1;
    const int dg = (ck < NCHUNK - 1) ? 1 : 0;
    const int grid = dg ? (4 + 1024) : 4;
    k_fused<<<grid, 512, 0, stream>>>(x, wcat, biasp, wbf, prod, cons,
                                      hcat, hstate, cstate,
                                      ck * CHUNK, (ck + 1) * CHUNK, 1, dg);
  }

  k_lnfc2<<<1024, 256, 0, stream>>>(hcat, lng, lnb, fcwb, fcb, out);
}

// Round 9
// 9106.100 us; speedup vs baseline: 1.2467x; 1.0803x over previous
//
#include <hip/hip_runtime.h>
#include <cstdint>
#include <cstddef>

// Problem dims
#define BDIM 32
#define TDIM 2048
#define IDIM 256
#define HDIM 256
#define CHUNK 128
#define NCHUNK (TDIM / CHUNK)

using short8 = __attribute__((ext_vector_type(8))) short;
using f32x4  = __attribute__((ext_vector_type(4))) float;
typedef _Float16 f16x8 __attribute__((ext_vector_type(8)));

__device__ __forceinline__ uint16_t f2bf(float f) {
  uint32_t u = __float_as_uint(f);
  uint32_t r = u + 0x7fffu + ((u >> 16) & 1u);   // RNE
  return (uint16_t)(r >> 16);
}
__device__ __forceinline__ uint16_t f2h_bits(float f) {
  _Float16 h = (_Float16)f;
  return __builtin_bit_cast(uint16_t, h);
}
__device__ __forceinline__ float h2lo(uint32_t u) {
  return (float)__builtin_bit_cast(_Float16, (uint16_t)u);
}
__device__ __forceinline__ float h2hi(uint32_t u) {
  return (float)__builtin_bit_cast(_Float16, (uint16_t)(u >> 16));
}
__device__ __forceinline__ float sigmoidf_fast(float x) {
  return 1.f / (1.f + __expf(-x));
}
__device__ __forceinline__ float tanhf_fast(float x) {
  float a = fabsf(x);
  float e = __expf(2.f * a);
  float t = 1.f - 2.f / (e + 1.f);
  return copysignf(t, x);
}

// ---------------- prep kernels ----------------

__global__ void k_cvt4(const float* __restrict__ src, uint16_t* __restrict__ dst, int n4) {
  int i = blockIdx.x * blockDim.x + threadIdx.x;
  if (i >= n4) return;
  const float4 v = ((const float4*)src)[i];
  ushort4 o;
  o.x = f2bf(v.x); o.y = f2bf(v.y); o.z = f2bf(v.z); o.w = f2bf(v.w);
  ((ushort4*)dst)[i] = o;
}

__global__ void k_zero_u32(uint32_t* __restrict__ p, int n) {
  int i = blockIdx.x * blockDim.x + threadIdx.x;
  if (i < n) p[i] = 0u;
}

// wcat[j][k] bf16: j = d*1024 + U*4 + g  -> Wih_d row = g*256 + U
__global__ void k_build_wcat3(const float* __restrict__ wf, const float* __restrict__ wb,
                              const float* __restrict__ biasf, const float* __restrict__ biasb,
                              uint16_t* __restrict__ wcat, float* __restrict__ biasp) {
  int id = blockIdx.x * 256 + threadIdx.x;    // 0 .. 524287
  int k = id & 255;
  int j = id >> 8;
  int d  = j >> 10;
  int jj = j & 1023;
  int U  = jj >> 2;
  int g  = jj & 3;
  const float* W = d ? wb : wf;
  const int row = g * 256 + U;
  wcat[id] = f2bf(W[row * 256 + k]);
  if (k == 0) biasp[j] = (d ? biasb : biasf)[row];
}

// wbf f16 MFMA B-frags: id = (((d*8+w)*8 + kt)*8 + nf)*512 + L*8 + j8
// g = nf>>1, n2 = nf&1, u = w*32 + n2*16 + (L&15), k = kt*32 + (L>>4)*8 + j8
// value = Whh_d[g*256 + u][k]
__global__ void k_build_wbf(const float* __restrict__ whf, const float* __restrict__ whb,
                            uint16_t* __restrict__ wbf) {
  int id = blockIdx.x * 256 + threadIdx.x;    // 0 .. 524287
  int j8 = id & 7;
  int L  = (id >> 3) & 63;
  int nf = (id >> 9) & 7;
  int kt = (id >> 12) & 7;
  int w  = (id >> 15) & 7;
  int d  = (id >> 18) & 1;
  int g = nf >> 1, n2 = nf & 1;
  int u = w * 32 + n2 * 16 + (L & 15);
  int k = kt * 32 + (L >> 4) * 8 + j8;
  const float* W = d ? whb : whf;
  wbf[id] = f2h_bits(W[(g * 256 + u) * 256 + k]);
}

// ---------------- fused: 4 recurrence WGs + GEMM WGs ----------------
// blocks 0..3: recurrence. bid = bh*2 + d. Each WG: 16 batches x one direction,
//   full 256 units. 512 thr = 8 waves. Weights FULLY resident: kt0-5 in 192 VGPRs,
//   kt6-7 in LDS (128 KB). ZERO per-step global weight traffic. h in LDS
//   MFMA-A-frag layout, double-buffered; 1 barrier/step. No cross-WG comm.
// blocks 4..1027: GEMM producing chunk c0g into xw_prod.
__global__ __launch_bounds__(512, 1) void k_fused(
    const float* __restrict__ x,          // [32][2048][256] f32
    const uint16_t* __restrict__ wcat,    // [2048][256] bf16
    const float* __restrict__ biasp,      // [2048]
    const uint16_t* __restrict__ wbf,     // MFMA B-frag Whh f16
    uint16_t* __restrict__ xw_prod,
    const uint16_t* __restrict__ xw_cons,
    uint16_t* __restrict__ hcat,          // [B][T][512] f16
    uint16_t* __restrict__ hstate,        // [4][4096] f16
    float* __restrict__ cstate,           // [4][512][8] f32
    int c0, int c0g, int do_lstm, int do_gemm) {
  __shared__ char smem[147456];           // rec: wlds 128KB + ha 16KB; gemm: Cs 33KB
  const int tid = threadIdx.x;
  const int bid = blockIdx.x;

  if (bid < 4) {
    // ---------------- recurrence ----------------
    if (!do_lstm) return;
    __builtin_amdgcn_s_setprio(1);

    uint16_t* wlds = (uint16_t*)smem;                 // [8 w][2 kt][8 nf][512] (kt6-7)
    uint16_t* ha   = (uint16_t*)(smem + 131072);      // [2][4096]

    const int d  = bid & 1;
    const int bh = bid >> 1;
    const int w    = tid >> 6;
    const int L    = tid & 63;
    const int l15  = L & 15;
    const int q4   = L >> 4;

    const uint16_t* wsb = wbf + (size_t)(d * 8 + w) * (8 * 8 * 512);

    // kt0-5 weight fragments -> 192 VGPRs (static-indexed, fully unrolled use)
    f16x8 wreg[6][8];
#pragma unroll
    for (int kt = 0; kt < 6; ++kt)
#pragma unroll
      for (int nf = 0; nf < 8; ++nf)
        wreg[kt][nf] = __builtin_bit_cast(f16x8,
            *(const short8*)(wsb + (kt * 8 + nf) * 512 + L * 8));

    // kt6-7 -> LDS (each wave stages its own slice)
#pragma unroll
    for (int kt = 0; kt < 2; ++kt)
#pragma unroll
      for (int nf = 0; nf < 8; ++nf)
        *(short8*)&wlds[((w * 2 + kt) * 8 + nf) * 512 + L * 8] =
            *(const short8*)(wsb + ((6 + kt) * 8 + nf) * 512 + L * 8);

    // h state -> ha[0]
    *(short8*)&ha[tid * 8] = *(const short8*)(hstate + bid * 4096 + tid * 8);

    float c[8];
#pragma unroll
    for (int i = 0; i < 8; ++i) c[i] = cstate[(bid * 512 + tid) * 8 + i];
    __syncthreads();

    const uint16_t* xwd = xw_cons + (size_t)bid * (CHUNK * 512 * 32);

    for (int sl = 0; sl < CHUNK; ++sl) {
      const int s = c0 + sl;
      const int t = d ? (TDIM - 1 - s) : s;
      const int rd = sl & 1;
      const uint16_t* harow = &ha[rd * 4096];
      uint16_t* hawr = &ha[(rd ^ 1) * 4096];
      const uint16_t* xp = xwd + ((size_t)sl * 512 + tid) * 32;

#pragma unroll
      for (int p = 0; p < 2; ++p) {
        const uint4 xqa = *(const uint4*)(xp + p * 16);
        const uint4 xqb = *(const uint4*)(xp + p * 16 + 8);

        f32x4 acc[4] = {};
#pragma unroll
        for (int kt = 0; kt < 6; ++kt) {
          const f16x8 af = __builtin_bit_cast(f16x8,
              *(const short8*)&harow[kt * 512 + L * 8]);
#pragma unroll
          for (int g = 0; g < 4; ++g)
            acc[g] = __builtin_amdgcn_mfma_f32_16x16x32_f16(af, wreg[kt][g * 2 + p], acc[g], 0, 0, 0);
        }
#pragma unroll
        for (int kt = 0; kt < 2; ++kt) {
          const f16x8 af = __builtin_bit_cast(f16x8,
              *(const short8*)&harow[(6 + kt) * 512 + L * 8]);
#pragma unroll
          for (int g = 0; g < 4; ++g) {
            const f16x8 bw = __builtin_bit_cast(f16x8,
                *(const short8*)&wlds[((w * 2 + kt) * 8 + g * 2 + p) * 512 + L * 8]);
            acc[g] = __builtin_amdgcn_mfma_f32_16x16x32_f16(af, bw, acc[g], 0, 0, 0);
          }
        }

        // nonlinearity: u = w*32 + p*16 + l15, b = q4*4 + r
        const uint32_t xw32[8] = { xqa.x, xqa.y, xqa.z, xqa.w, xqb.x, xqb.y, xqb.z, xqb.w };
        const int u = w * 32 + p * 16 + l15;
        const int lpbase = 16 * ((p * 2 + (l15 >> 3)) & 3);
#pragma unroll
        for (int r = 0; r < 4; ++r) {
          const uint32_t w01 = xw32[r * 2];
          const uint32_t w23 = xw32[r * 2 + 1];
          const float gi = acc[0][r] + h2lo(w01);
          const float gf = acc[1][r] + h2hi(w01);
          const float gg = acc[2][r] + h2lo(w23);
          const float go = acc[3][r] + h2hi(w23);
          const float I = sigmoidf_fast(gi);
          const float F = sigmoidf_fast(gf);
          const float G = tanhf_fast(gg);
          const float O = sigmoidf_fast(go);
          float& cc = c[p * 4 + r];
          cc = F * cc + I * G;
          const float h = O * tanhf_fast(cc);
          const uint16_t hb = f2h_bits(h);
          const int b = q4 * 4 + r;
          hawr[w * 512 + (b + lpbase) * 8 + (l15 & 7)] = hb;
          hcat[((size_t)((bh * 16 + b) * TDIM + t)) * 512 + d * 256 + u] = hb;
        }
      }
      __syncthreads();
    }

    // save state (CHUNK even -> final h in ha[0])
    *(short8*)(hstate + bid * 4096 + tid * 8) = *(const short8*)&ha[tid * 8];
#pragma unroll
    for (int i = 0; i < 8; ++i) cstate[(bid * 512 + tid) * 8 + i] = c[i];
    return;
  }

  // ---------------- GEMM: produce chunk c0g ----------------
  if (!do_gemm) return;
  float* Cs = (float*)smem;               // [32][260]
  const int gid = bid - 4;                // 0..1023
  const int mt  = gid >> 3;               // 128 m-tiles = sl
  const int nt8 = gid & 7;                // 8 n-tiles of 256 cols
  const int d  = nt8 >> 2;
  const int dn = nt8 & 3;
  const int wv = tid >> 6;
  const int mh = wv & 1;                  // = bh
  const int nq = wv >> 1;
  const int L = tid & 63;
  const int l15 = L & 15;
  const int lg  = L >> 4;

  const int jbase = d * 1024 + dn * 256 + nq * 64;
  const int t = d ? (TDIM - 1 - (c0g + mt)) : (c0g + mt);
  const float* Abase = x + ((size_t)((mh * 16 + l15) * TDIM + t)) * 256 + lg * 8;

  f32x4 acc[4] = {};
#pragma unroll
  for (int ks = 0; ks < 8; ++ks) {
    const float4 f0 = *(const float4*)(Abase + ks * 32);
    const float4 f1 = *(const float4*)(Abase + ks * 32 + 4);
    short8 a;
    a[0] = (short)f2bf(f0.x); a[1] = (short)f2bf(f0.y);
    a[2] = (short)f2bf(f0.z); a[3] = (short)f2bf(f0.w);
    a[4] = (short)f2bf(f1.x); a[5] = (short)f2bf(f1.y);
    a[6] = (short)f2bf(f1.z); a[7] = (short)f2bf(f1.w);
#pragma unroll
    for (int nf = 0; nf < 4; ++nf) {
      const short8 bfr = *(const short8*)(wcat + (size_t)(jbase + nf * 16 + l15) * 256 + ks * 32 + lg * 8);
      acc[nf] = __builtin_amdgcn_mfma_f32_16x16x32_bf16(a, bfr, acc[nf], 0, 0, 0);
    }
  }
#pragma unroll
  for (int nf = 0; nf < 4; ++nf) {
    const float bv = biasp[jbase + nf * 16 + l15];
    const int col = nq * 64 + nf * 16 + l15;
#pragma unroll
    for (int r = 0; r < 4; ++r)
      Cs[(mh * 16 + lg * 4 + r) * 260 + col] = acc[nf][r] + bv;
  }
  __syncthreads();

  // scatter into recurrence-native layout: [bh*2+d][sl][tid2][32 f16]
#pragma unroll
  for (int i = 0; i < 4; ++i) {
    const int o = tid * 4 + i;            // 0..2047
    const int rr = o >> 6;                // batch row 0..31
    const int uloc = o & 63;
    const float f0 = Cs[rr * 260 + uloc * 4 + 0];
    const float f1 = Cs[rr * 260 + uloc * 4 + 1];
    const float f2 = Cs[rr * 260 + uloc * 4 + 2];
    const float f3 = Cs[rr * 260 + uloc * 4 + 3];
    const int U = dn * 64 + uloc;
    const int bh_o = rr >> 4;
    const int b16 = rr & 15;
    const int tid2 = (U >> 5) * 64 + (b16 >> 2) * 16 + (U & 15);
    const int e0 = (((U >> 4) & 1) * 4 + (b16 & 3)) * 4;
    uint2 v;
    v.x = (uint32_t)f2h_bits(f0) | ((uint32_t)f2h_bits(f1) << 16);
    v.y = (uint32_t)f2h_bits(f2) | ((uint32_t)f2h_bits(f3) << 16);
    *(uint2*)(xw_prod + ((size_t)(bh_o * 2 + d) * CHUNK + mt) * (512 * 32) + tid2 * 32 + e0) = v;
  }
}

// ---------------- LayerNorm + FC (MFMA) ----------------
__global__ __launch_bounds__(256) void k_lnfc2(
    const uint16_t* __restrict__ hcat,
    const float* __restrict__ lng, const float* __restrict__ lnb,
    const uint16_t* __restrict__ fcwb,  // [256][512] bf16
    const float* __restrict__ fcb,
    float* __restrict__ out) {
  __shared__ uint16_t lnh[64 * 520];
  __shared__ float slng[512], slnb[512];

  const int tid = threadIdx.x;
  const size_t bt0 = (size_t)blockIdx.x * 64;

  slng[tid] = lng[tid]; slng[tid + 256] = lng[tid + 256];
  slnb[tid] = lnb[tid]; slnb[tid + 256] = lnb[tid + 256];

  const int row = tid >> 2;
  const int part = tid & 3;
  const uint16_t* hrow = hcat + (bt0 + row) * 512;
  float s = 0.f, s2 = 0.f;
#pragma unroll
  for (int i = 0; i < 16; ++i) {
    const uint4 u = *(const uint4*)(hrow + (i * 4 + part) * 8);
    const float f0 = h2lo(u.x), f1 = h2hi(u.x), f2 = h2lo(u.y), f3 = h2hi(u.y);
    const float f4 = h2lo(u.z), f5 = h2hi(u.z), f6 = h2lo(u.w), f7 = h2hi(u.w);
    s  += ((f0 + f1) + (f2 + f3)) + ((f4 + f5) + (f6 + f7));
    s2 += ((f0*f0 + f1*f1) + (f2*f2 + f3*f3)) + ((f4*f4 + f5*f5) + (f6*f6 + f7*f7));
  }
  s  += __shfl_xor(s, 1, 64);  s  += __shfl_xor(s, 2, 64);
  s2 += __shfl_xor(s2, 1, 64); s2 += __shfl_xor(s2, 2, 64);
  const float mu = s * (1.f / 512.f);
  const float var = s2 * (1.f / 512.f) - mu * mu;
  const float rs = rsqrtf(var + 1e-5f);
  __syncthreads();

#pragma unroll
  for (int i = 0; i < 16; ++i) {
    const int kb = (i * 4 + part) * 8;
    const uint4 u = *(const uint4*)(hrow + kb);
    uint16_t tmp[8] __attribute__((aligned(16)));
    const float f[8] = { h2lo(u.x), h2hi(u.x), h2lo(u.y), h2hi(u.y),
                         h2lo(u.z), h2hi(u.z), h2lo(u.w), h2hi(u.w) };
#pragma unroll
    for (int e = 0; e < 8; ++e)
      tmp[e] = f2bf((f[e] - mu) * rs * slng[kb + e] + slnb[kb + e]);
    *(short8*)&lnh[row * 520 + kb] = *(const short8*)tmp;
  }
  __syncthreads();

  const int w = tid >> 6;
  const int lane = tid & 63;
  const int l15 = lane & 15;
  const int lg = lane >> 4;
  f32x4 acc[4][4] = {};
#pragma unroll
  for (int nf = 0; nf < 4; ++nf) {
    const uint16_t* bb = fcwb + (size_t)(w * 64 + nf * 16 + l15) * 512 + lg * 8;
#pragma unroll 4
    for (int k0 = 0; k0 < 16; ++k0) {
      const short8 bfr = *(const short8*)(bb + k0 * 32);
#pragma unroll
      for (int mf = 0; mf < 4; ++mf) {
        const short8 afr = *(const short8*)&lnh[(mf * 16 + l15) * 520 + k0 * 32 + lg * 8];
        acc[mf][nf] = __builtin_amdgcn_mfma_f32_16x16x32_bf16(afr, bfr, acc[mf][nf], 0, 0, 0);
      }
    }
  }
#pragma unroll
  for (int nf = 0; nf < 4; ++nf) {
    const int col = w * 64 + nf * 16 + l15;
    const float fv = fcb[col];
#pragma unroll
    for (int mf = 0; mf < 4; ++mf)
#pragma unroll
      for (int r = 0; r < 4; ++r)
        out[(bt0 + mf * 16 + lg * 4 + r) * 256 + col] = acc[mf][nf][r] + fv;
  }
}

// ---------------- launcher ----------------

extern "C" void kernel_launch(void* const* d_in, const int* in_sizes, int n_in,
                              void* d_out, int out_size, void* d_ws, size_t ws_size,
                              hipStream_t stream) {
  const float* x    = (const float*)d_in[0];
  const float* Wihf = (const float*)d_in[1];
  const float* Whhf = (const float*)d_in[2];
  const float* bf_  = (const float*)d_in[3];
  const float* Wihb = (const float*)d_in[4];
  const float* Whhb = (const float*)d_in[5];
  const float* bb_  = (const float*)d_in[6];
  const float* lng  = (const float*)d_in[7];
  const float* lnb  = (const float*)d_in[8];
  const float* fcW  = (const float*)d_in[9];
  const float* fcb  = (const float*)d_in[10];
  float* out = (float*)d_out;

  char* ws = (char*)d_ws;
  size_t off = 0;
  uint16_t* wcat   = (uint16_t*)(ws + off); off += (size_t)2048 * 256 * 2;            // 1.0 MB
  float*    biasp  = (float*)(ws + off);    off += (size_t)2048 * 4;                  // 8 KB
  uint16_t* wbf    = (uint16_t*)(ws + off); off += (size_t)524288 * 2;                // 1.0 MB
  uint16_t* fcwb   = (uint16_t*)(ws + off); off += (size_t)256 * 512 * 2;             // 0.26 MB
  float*    cstate = (float*)(ws + off);    off += (size_t)4 * 512 * 8 * 4;           // 64 KB
  uint16_t* hstate = (uint16_t*)(ws + off); off += (size_t)4 * 4096 * 2;              // 32 KB
  uint16_t* xw0    = (uint16_t*)(ws + off); off += (size_t)4 * CHUNK * 512 * 32 * 2;  // 16.8 MB
  uint16_t* xw1    = (uint16_t*)(ws + off); off += (size_t)4 * CHUNK * 512 * 32 * 2;  // 16.8 MB
  uint16_t* hcat   = (uint16_t*)(ws + off); off += (size_t)65536 * 512 * 2;           // 67 MB
  (void)ws_size; (void)in_sizes; (void)n_in; (void)out_size;
  // total ~103 MB

  // prep (each call: cstate/hstate re-zeroed for graph-replay determinism)
  k_cvt4<<<128, 256, 0, stream>>>(fcW, fcwb, 131072 / 4);
  k_build_wcat3<<<2048, 256, 0, stream>>>(Wihf, Wihb, bf_, bb_, wcat, biasp);
  k_build_wbf<<<2048, 256, 0, stream>>>(Whhf, Whhb, wbf);
  // cstate(64KB)+hstate(32KB) contiguous = 24576 u32
  k_zero_u32<<<96, 256, 0, stream>>>((uint32_t*)cstate, 24576);

  // prologue: GEMM chunk 0 -> xw0
  k_fused<<<4 + 1024, 512, 0, stream>>>(x, wcat, biasp, wbf, xw0, xw1,
                                        hcat, hstate, cstate, 0, 0, 0, 1);

  for (int ck = 0; ck < NCHUNK; ++ck) {
    uint16_t* cons = (ck & 1) ? xw1 : xw0;
    uint16_t* prod = (ck & 1) ? xw0 : xw1;
    const int dg = (ck < NCHUNK - 1) ? 1 : 0;
    const int grid = dg ? (4 + 1024) : 4;
    k_fused<<<grid, 512, 0, stream>>>(x, wcat, biasp, wbf, prod, cons,
                                      hcat, hstate, cstate,
                                      ck * CHUNK, (ck + 1) * CHUNK, 1, dg);
  }

  k_lnfc2<<<1024, 256, 0, stream>>>(hcat, lng, lnb, fcwb, fcb, out);
}

// Round 11
// 8794.186 us; speedup vs baseline: 1.2910x; 1.0355x over previous
//
#include <hip/hip_runtime.h>
#include <cstdint>
#include <cstddef>

// Problem dims
#define BDIM 32
#define TDIM 2048
#define IDIM 256
#define HDIM 256
#define CHUNK 128
#define NCHUNK (TDIM / CHUNK)

using short8 = __attribute__((ext_vector_type(8))) short;
using f32x4  = __attribute__((ext_vector_type(4))) float;
typedef _Float16 f16x8 __attribute__((ext_vector_type(8)));

__device__ __forceinline__ uint16_t f2bf(float f) {
  uint32_t u = __float_as_uint(f);
  uint32_t r = u + 0x7fffu + ((u >> 16) & 1u);   // RNE
  return (uint16_t)(r >> 16);
}
__device__ __forceinline__ uint16_t f2h_bits(float f) {
  _Float16 h = (_Float16)f;
  return __builtin_bit_cast(uint16_t, h);
}
__device__ __forceinline__ float h2lo(uint32_t u) {
  return (float)__builtin_bit_cast(_Float16, (uint16_t)u);
}
__device__ __forceinline__ float h2hi(uint32_t u) {
  return (float)__builtin_bit_cast(_Float16, (uint16_t)(u >> 16));
}
__device__ __forceinline__ float sigmoidf_fast(float x) {
  return 1.f / (1.f + __expf(-x));
}
__device__ __forceinline__ float tanhf_fast(float x) {
  float a = fabsf(x);
  float e = __expf(2.f * a);
  float t = 1.f - 2.f / (e + 1.f);
  return copysignf(t, x);
}

// ---------------- prep kernels ----------------

__global__ void k_cvt4(const float* __restrict__ src, uint16_t* __restrict__ dst, int n4) {
  int i = blockIdx.x * blockDim.x + threadIdx.x;
  if (i >= n4) return;
  const float4 v = ((const float4*)src)[i];
  ushort4 o;
  o.x = f2bf(v.x); o.y = f2bf(v.y); o.z = f2bf(v.z); o.w = f2bf(v.w);
  ((ushort4*)dst)[i] = o;
}

__global__ void k_zero_u32(uint32_t* __restrict__ p, int n) {
  int i = blockIdx.x * blockDim.x + threadIdx.x;
  if (i < n) p[i] = 0u;
}

// wcat[j][k] bf16: j = d*1024 + U*4 + g  -> Wih_d row = g*256 + U
__global__ void k_build_wcat3(const float* __restrict__ wf, const float* __restrict__ wb,
                              const float* __restrict__ biasf, const float* __restrict__ biasb,
                              uint16_t* __restrict__ wcat, float* __restrict__ biasp) {
  int id = blockIdx.x * 256 + threadIdx.x;    // 0 .. 524287
  int k = id & 255;
  int j = id >> 8;
  int d  = j >> 10;
  int jj = j & 1023;
  int U  = jj >> 2;
  int g  = jj & 3;
  const float* W = d ? wb : wf;
  const int row = g * 256 + U;
  wcat[id] = f2bf(W[row * 256 + k]);
  if (k == 0) biasp[j] = (d ? biasb : biasf)[row];
}

// wbf f16 MFMA B-frags: id = (((d*8+w)*8 + kt)*8 + nf)*512 + L*8 + j8
// g = nf>>1, n2 = nf&1, u = w*32 + n2*16 + (L&15), k = kt*32 + (L>>4)*8 + j8
// value = Whh_d[g*256 + u][k]
__global__ void k_build_wbf(const float* __restrict__ whf, const float* __restrict__ whb,
                            uint16_t* __restrict__ wbf) {
  int id = blockIdx.x * 256 + threadIdx.x;    // 0 .. 524287
  int j8 = id & 7;
  int L  = (id >> 3) & 63;
  int nf = (id >> 9) & 7;
  int kt = (id >> 12) & 7;
  int w  = (id >> 15) & 7;
  int d  = (id >> 18) & 1;
  int g = nf >> 1, n2 = nf & 1;
  int u = w * 32 + n2 * 16 + (L & 15);
  int k = kt * 32 + (L >> 4) * 8 + j8;
  const float* W = d ? whb : whf;
  wbf[id] = f2h_bits(W[(g * 256 + u) * 256 + k]);
}

// ---------------- fused: 4 recurrence WGs + GEMM WGs ----------------
// blocks 0..3: recurrence. bid = bh*2 + d. Each WG: 16 batches x one direction,
//   full 256 units. 512 thr = 8 waves. Weights FULLY resident: kt0-5 pinned in
//   192 VGPRs via per-component empty-asm (defeats load rematerialization),
//   kt6-7 in LDS (128 KB). ZERO per-step global weight traffic. h in LDS
//   MFMA-A-frag layout, double-buffered; 1 barrier/step. No cross-WG comm.
// blocks 4..1027: GEMM producing chunk c0g into xw_prod.
__global__ __launch_bounds__(512, 1) void k_fused(
    const float* __restrict__ x,          // [32][2048][256] f32
    const uint16_t* __restrict__ wcat,    // [2048][256] bf16
    const float* __restrict__ biasp,      // [2048]
    const uint16_t* __restrict__ wbf,     // MFMA B-frag Whh f16
    uint16_t* __restrict__ xw_prod,
    const uint16_t* __restrict__ xw_cons,
    uint16_t* __restrict__ hcat,          // [B][T][512] f16
    uint16_t* __restrict__ hstate,        // [4][4096] f16
    float* __restrict__ cstate,           // [4][512][8] f32
    int c0, int c0g, int do_lstm, int do_gemm) {
  __shared__ char smem[147456];           // rec: wlds 128KB + ha 16KB; gemm: Cs 33KB
  const int tid = threadIdx.x;
  const int bid = blockIdx.x;

  if (bid < 4) {
    // ---------------- recurrence ----------------
    if (!do_lstm) return;
    __builtin_amdgcn_s_setprio(1);

    uint16_t* wlds = (uint16_t*)smem;                 // [8 w][2 kt][8 nf][512] (kt6-7)
    uint16_t* ha   = (uint16_t*)(smem + 131072);      // [2][4096]

    const int d  = bid & 1;
    const int bh = bid >> 1;
    const int w    = tid >> 6;
    const int L    = tid & 63;
    const int l15  = L & 15;
    const int q4   = L >> 4;

    const uint16_t* wsb = wbf + (size_t)(d * 8 + w) * (8 * 8 * 512);

    // kt0-5 weight fragments -> 192 VGPRs, PINNED against rematerialization.
    // Per-component scalar "+v" asm (128-bit tied operands are unsupported):
    // the asm output is opaque, so the compiler must keep the value resident
    // instead of re-loading from global inside the step loop.
    f16x8 wreg[6][8];
#pragma unroll
    for (int kt = 0; kt < 6; ++kt)
#pragma unroll
      for (int nf = 0; nf < 8; ++nf) {
        uint4 tmp = *(const uint4*)(wsb + (kt * 8 + nf) * 512 + L * 8);
        asm volatile("" : "+v"(tmp.x), "+v"(tmp.y), "+v"(tmp.z), "+v"(tmp.w));
        wreg[kt][nf] = __builtin_bit_cast(f16x8, tmp);
      }

    // kt6-7 -> LDS (each wave stages its own slice)
#pragma unroll
    for (int kt = 0; kt < 2; ++kt)
#pragma unroll
      for (int nf = 0; nf < 8; ++nf)
        *(short8*)&wlds[((w * 2 + kt) * 8 + nf) * 512 + L * 8] =
            *(const short8*)(wsb + ((6 + kt) * 8 + nf) * 512 + L * 8);

    // h state -> ha[0]
    *(short8*)&ha[tid * 8] = *(const short8*)(hstate + bid * 4096 + tid * 8);

    float c[8];
#pragma unroll
    for (int i = 0; i < 8; ++i) c[i] = cstate[(bid * 512 + tid) * 8 + i];
    __syncthreads();

    const uint16_t* xwd = xw_cons + (size_t)bid * (CHUNK * 512 * 32);

    for (int sl = 0; sl < CHUNK; ++sl) {
      const int s = c0 + sl;
      const int t = d ? (TDIM - 1 - s) : s;
      const int rd = sl & 1;
      const uint16_t* harow = &ha[rd * 4096];
      uint16_t* hawr = &ha[(rd ^ 1) * 4096];
      const uint16_t* xp = xwd + ((size_t)sl * 512 + tid) * 32;

#pragma unroll
      for (int p = 0; p < 2; ++p) {
        const uint4 xqa = *(const uint4*)(xp + p * 16);
        const uint4 xqb = *(const uint4*)(xp + p * 16 + 8);

        f32x4 acc[4] = {};
#pragma unroll
        for (int kt = 0; kt < 6; ++kt) {
          const f16x8 af = __builtin_bit_cast(f16x8,
              *(const short8*)&harow[kt * 512 + L * 8]);
#pragma unroll
          for (int g = 0; g < 4; ++g)
            acc[g] = __builtin_amdgcn_mfma_f32_16x16x32_f16(af, wreg[kt][g * 2 + p], acc[g], 0, 0, 0);
        }
#pragma unroll
        for (int kt = 0; kt < 2; ++kt) {
          const f16x8 af = __builtin_bit_cast(f16x8,
              *(const short8*)&harow[(6 + kt) * 512 + L * 8]);
#pragma unroll
          for (int g = 0; g < 4; ++g) {
            const f16x8 bw = __builtin_bit_cast(f16x8,
                *(const short8*)&wlds[((w * 2 + kt) * 8 + g * 2 + p) * 512 + L * 8]);
            acc[g] = __builtin_amdgcn_mfma_f32_16x16x32_f16(af, bw, acc[g], 0, 0, 0);
          }
        }

        // nonlinearity: u = w*32 + p*16 + l15, b = q4*4 + r
        const uint32_t xw32[8] = { xqa.x, xqa.y, xqa.z, xqa.w, xqb.x, xqb.y, xqb.z, xqb.w };
        const int u = w * 32 + p * 16 + l15;
        const int lpbase = 16 * ((p * 2 + (l15 >> 3)) & 3);
#pragma unroll
        for (int r = 0; r < 4; ++r) {
          const uint32_t w01 = xw32[r * 2];
          const uint32_t w23 = xw32[r * 2 + 1];
          const float gi = acc[0][r] + h2lo(w01);
          const float gf = acc[1][r] + h2hi(w01);
          const float gg = acc[2][r] + h2lo(w23);
          const float go = acc[3][r] + h2hi(w23);
          const float I = sigmoidf_fast(gi);
          const float F = sigmoidf_fast(gf);
          const float G = tanhf_fast(gg);
          const float O = sigmoidf_fast(go);
          float& cc = c[p * 4 + r];
          cc = F * cc + I * G;
          const float h = O * tanhf_fast(cc);
          const uint16_t hb = f2h_bits(h);
          const int b = q4 * 4 + r;
          hawr[w * 512 + (b + lpbase) * 8 + (l15 & 7)] = hb;
          hcat[((size_t)((bh * 16 + b) * TDIM + t)) * 512 + d * 256 + u] = hb;
        }
      }
      __syncthreads();
    }

    // save state (CHUNK even -> final h in ha[0])
    *(short8*)(hstate + bid * 4096 + tid * 8) = *(const short8*)&ha[tid * 8];
#pragma unroll
    for (int i = 0; i < 8; ++i) cstate[(bid * 512 + tid) * 8 + i] = c[i];
    return;
  }

  // ---------------- GEMM: produce chunk c0g ----------------
  if (!do_gemm) return;
  float* Cs = (float*)smem;               // [32][260]
  const int gid = bid - 4;                // 0..1023
  const int mt  = gid >> 3;               // 128 m-tiles = sl
  const int nt8 = gid & 7;                // 8 n-tiles of 256 cols
  const int d  = nt8 >> 2;
  const int dn = nt8 & 3;
  const int wv = tid >> 6;
  const int mh = wv & 1;                  // = bh
  const int nq = wv >> 1;
  const int L = tid & 63;
  const int l15 = L & 15;
  const int lg  = L >> 4;

  const int jbase = d * 1024 + dn * 256 + nq * 64;
  const int t = d ? (TDIM - 1 - (c0g + mt)) : (c0g + mt);
  const float* Abase = x + ((size_t)((mh * 16 + l15) * TDIM + t)) * 256 + lg * 8;

  f32x4 acc[4] = {};
#pragma unroll
  for (int ks = 0; ks < 8; ++ks) {
    const float4 f0 = *(const float4*)(Abase + ks * 32);
    const float4 f1 = *(const float4*)(Abase + ks * 32 + 4);
    short8 a;
    a[0] = (short)f2bf(f0.x); a[1] = (short)f2bf(f0.y);
    a[2] = (short)f2bf(f0.z); a[3] = (short)f2bf(f0.w);
    a[4] = (short)f2bf(f1.x); a[5] = (short)f2bf(f1.y);
    a[6] = (short)f2bf(f1.z); a[7] = (short)f2bf(f1.w);
#pragma unroll
    for (int nf = 0; nf < 4; ++nf) {
      const short8 bfr = *(const short8*)(wcat + (size_t)(jbase + nf * 16 + l15) * 256 + ks * 32 + lg * 8);
      acc[nf] = __builtin_amdgcn_mfma_f32_16x16x32_bf16(a, bfr, acc[nf], 0, 0, 0);
    }
  }
#pragma unroll
  for (int nf = 0; nf < 4; ++nf) {
    const float bv = biasp[jbase + nf * 16 + l15];
    const int col = nq * 64 + nf * 16 + l15;
#pragma unroll
    for (int r = 0; r < 4; ++r)
      Cs[(mh * 16 + lg * 4 + r) * 260 + col] = acc[nf][r] + bv;
  }
  __syncthreads();

  // scatter into recurrence-native layout: [bh*2+d][sl][tid2][32 f16]
#pragma unroll
  for (int i = 0; i < 4; ++i) {
    const int o = tid * 4 + i;            // 0..2047
    const int rr = o >> 6;                // batch row 0..31
    const int uloc = o & 63;
    const float f0 = Cs[rr * 260 + uloc * 4 + 0];
    const float f1 = Cs[rr * 260 + uloc * 4 + 1];
    const float f2 = Cs[rr * 260 + uloc * 4 + 2];
    const float f3 = Cs[rr * 260 + uloc * 4 + 3];
    const int U = dn * 64 + uloc;
    const int bh_o = rr >> 4;
    const int b16 = rr & 15;
    const int tid2 = (U >> 5) * 64 + (b16 >> 2) * 16 + (U & 15);
    const int e0 = (((U >> 4) & 1) * 4 + (b16 & 3)) * 4;
    uint2 v;
    v.x = (uint32_t)f2h_bits(f0) | ((uint32_t)f2h_bits(f1) << 16);
    v.y = (uint32_t)f2h_bits(f2) | ((uint32_t)f2h_bits(f3) << 16);
    *(uint2*)(xw_prod + ((size_t)(bh_o * 2 + d) * CHUNK + mt) * (512 * 32) + tid2 * 32 + e0) = v;
  }
}

// ---------------- LayerNorm + FC (MFMA) ----------------
__global__ __launch_bounds__(256) void k_lnfc2(
    const uint16_t* __restrict__ hcat,
    const float* __restrict__ lng, const float* __restrict__ lnb,
    const uint16_t* __restrict__ fcwb,  // [256][512] bf16
    const float* __restrict__ fcb,
    float* __restrict__ out) {
  __shared__ uint16_t lnh[64 * 520];
  __shared__ float slng[512], slnb[512];

  const int tid = threadIdx.x;
  const size_t bt0 = (size_t)blockIdx.x * 64;

  slng[tid] = lng[tid]; slng[tid + 256] = lng[tid + 256];
  slnb[tid] = lnb[tid]; slnb[tid + 256] = lnb[tid + 256];

  const int row = tid >> 2;
  const int part = tid & 3;
  const uint16_t* hrow = hcat + (bt0 + row) * 512;
  float s = 0.f, s2 = 0.f;
#pragma unroll
  for (int i = 0; i < 16; ++i) {
    const uint4 u = *(const uint4*)(hrow + (i * 4 + part) * 8);
    const float f0 = h2lo(u.x), f1 = h2hi(u.x), f2 = h2lo(u.y), f3 = h2hi(u.y);
    const float f4 = h2lo(u.z), f5 = h2hi(u.z), f6 = h2lo(u.w), f7 = h2hi(u.w);
    s  += ((f0 + f1) + (f2 + f3)) + ((f4 + f5) + (f6 + f7));
    s2 += ((f0*f0 + f1*f1) + (f2*f2 + f3*f3)) + ((f4*f4 + f5*f5) + (f6*f6 + f7*f7));
  }
  s  += __shfl_xor(s, 1, 64);  s  += __shfl_xor(s, 2, 64);
  s2 += __shfl_xor(s2, 1, 64); s2 += __shfl_xor(s2, 2, 64);
  const float mu = s * (1.f / 512.f);
  const float var = s2 * (1.f / 512.f) - mu * mu;
  const float rs = rsqrtf(var + 1e-5f);
  __syncthreads();

#pragma unroll
  for (int i = 0; i < 16; ++i) {
    const int kb = (i * 4 + part) * 8;
    const uint4 u = *(const uint4*)(hrow + kb);
    uint16_t tmp[8] __attribute__((aligned(16)));
    const float f[8] = { h2lo(u.x), h2hi(u.x), h2lo(u.y), h2hi(u.y),
                         h2lo(u.z), h2hi(u.z), h2lo(u.w), h2hi(u.w) };
#pragma unroll
    for (int e = 0; e < 8; ++e)
      tmp[e] = f2bf((f[e] - mu) * rs * slng[kb + e] + slnb[kb + e]);
    *(short8*)&lnh[row * 520 + kb] = *(const short8*)tmp;
  }
  __syncthreads();

  const int w = tid >> 6;
  const int lane = tid & 63;
  const int l15 = lane & 15;
  const int lg = lane >> 4;
  f32x4 acc[4][4] = {};
#pragma unroll
  for (int nf = 0; nf < 4; ++nf) {
    const uint16_t* bb = fcwb + (size_t)(w * 64 + nf * 16 + l15) * 512 + lg * 8;
#pragma unroll 4
    for (int k0 = 0; k0 < 16; ++k0) {
      const short8 bfr = *(const short8*)(bb + k0 * 32);
#pragma unroll
      for (int mf = 0; mf < 4; ++mf) {
        const short8 afr = *(const short8*)&lnh[(mf * 16 + l15) * 520 + k0 * 32 + lg * 8];
        acc[mf][nf] = __builtin_amdgcn_mfma_f32_16x16x32_bf16(afr, bfr, acc[mf][nf], 0, 0, 0);
      }
    }
  }
#pragma unroll
  for (int nf = 0; nf < 4; ++nf) {
    const int col = w * 64 + nf * 16 + l15;
    const float fv = fcb[col];
#pragma unroll
    for (int mf = 0; mf < 4; ++mf)
#pragma unroll
      for (int r = 0; r < 4; ++r)
        out[(bt0 + mf * 16 + lg * 4 + r) * 256 + col] = acc[mf][nf][r] + fv;
  }
}

// ---------------- launcher ----------------

extern "C" void kernel_launch(void* const* d_in, const int* in_sizes, int n_in,
                              void* d_out, int out_size, void* d_ws, size_t ws_size,
                              hipStream_t stream) {
  const float* x    = (const float*)d_in[0];
  const float* Wihf = (const float*)d_in[1];
  const float* Whhf = (const float*)d_in[2];
  const float* bf_  = (const float*)d_in[3];
  const float* Wihb = (const float*)d_in[4];
  const float* Whhb = (const float*)d_in[5];
  const float* bb_  = (const float*)d_in[6];
  const float* lng  = (const float*)d_in[7];
  const float* lnb  = (const float*)d_in[8];
  const float* fcW  = (const float*)d_in[9];
  const float* fcb  = (const float*)d_in[10];
  float* out = (float*)d_out;

  char* ws = (char*)d_ws;
  size_t off = 0;
  uint16_t* wcat   = (uint16_t*)(ws + off); off += (size_t)2048 * 256 * 2;            // 1.0 MB
  float*    biasp  = (float*)(ws + off);    off += (size_t)2048 * 4;                  // 8 KB
  uint16_t* wbf    = (uint16_t*)(ws + off); off += (size_t)524288 * 2;                // 1.0 MB
  uint16_t* fcwb   = (uint16_t*)(ws + off); off += (size_t)256 * 512 * 2;             // 0.26 MB
  float*    cstate = (float*)(ws + off);    off += (size_t)4 * 512 * 8 * 4;           // 64 KB
  uint16_t* hstate = (uint16_t*)(ws + off); off += (size_t)4 * 4096 * 2;              // 32 KB
  uint16_t* xw0    = (uint16_t*)(ws + off); off += (size_t)4 * CHUNK * 512 * 32 * 2;  // 16.8 MB
  uint16_t* xw1    = (uint16_t*)(ws + off); off += (size_t)4 * CHUNK * 512 * 32 * 2;  // 16.8 MB
  uint16_t* hcat   = (uint16_t*)(ws + off); off += (size_t)65536 * 512 * 2;           // 67 MB
  (void)ws_size; (void)in_sizes; (void)n_in; (void)out_size;
  // total ~103 MB

  // prep (each call: cstate/hstate re-zeroed for graph-replay determinism)
  k_cvt4<<<128, 256, 0, stream>>>(fcW, fcwb, 131072 / 4);
  k_build_wcat3<<<2048, 256, 0, stream>>>(Wihf, Wihb, bf_, bb_, wcat, biasp);
  k_build_wbf<<<2048, 256, 0, stream>>>(Whhf, Whhb, wbf);
  // cstate(64KB)+hstate(32KB) contiguous = 24576 u32
  k_zero_u32<<<96, 256, 0, stream>>>((uint32_t*)cstate, 24576);

  // prologue: GEMM chunk 0 -> xw0
  k_fused<<<4 + 1024, 512, 0, stream>>>(x, wcat, biasp, wbf, xw0, xw1,
                                        hcat, hstate, cstate, 0, 0, 0, 1);

  for (int ck = 0; ck < NCHUNK; ++ck) {
    uint16_t* cons = (ck & 1) ? xw1 : xw0;
    uint16_t* prod = (ck & 1) ? xw0 : xw1;
    const int dg = (ck < NCHUNK - 1) ? 1 : 0;
    const int grid = dg ? (4 + 1024) : 4;
    k_fused<<<grid, 512, 0, stream>>>(x, wcat, biasp, wbf, prod, cons,
                                      hcat, hstate, cstate,
                                      ck * CHUNK, (ck + 1) * CHUNK, 1, dg);
  }

  k_lnfc2<<<1024, 256, 0, stream>>>(hcat, lng, lnb, fcwb, fcb, out);
}